// Round 6
// baseline (875.236 us; speedup 1.0000x reference)
//
#include <hip/hip_runtime.h>

#define N_NODES 100000
#define N_EDGES 3200000
#define N_PAD   100096
#define BNODES  128                         // nodes per bucket
#define NBUCK   ((N_NODES + BNODES - 1) / BNODES)   // 782
#define BCAP    4800                        // slots per bucket (mean 4096, sigma 64)
#define EPB_BIN 8192                        // edges per bin block (32/thread)
#define BIN_BLOCKS ((N_EDGES + EPB_BIN - 1) / EPB_BIN)  // 391
#define SPILL_MAX 65536
#define SCAN_CHUNK 2048
#define SCAN_BLOCKS ((N_NODES + SCAN_CHUNK - 1) / SCAN_CHUNK)

typedef unsigned int uint;

// ===================== bucket fast path =====================

// zero bucket_cnt + spill_cnt
__global__ __launch_bounds__(256) void k_zero(int* __restrict__ bucket_cnt,
                                              int* __restrict__ spill_cnt) {
    int i = blockIdx.x * blockDim.x + threadIdx.x;
    if (i < NBUCK) bucket_cnt[i] = 0;
    if (i == 0) *spill_cnt = 0;
}

// counting-sort edges into 782 dst-buckets; entry = { (dstl<<17)|src , w_bits }
__global__ __launch_bounds__(256) void k_bin(const int* __restrict__ src,
                                             const int* __restrict__ dst,
                                             const float* __restrict__ w,
                                             int* __restrict__ bucket_cnt,
                                             uint2* __restrict__ ebuf,
                                             int4* __restrict__ sp,
                                             int* __restrict__ spill_cnt) {
    __shared__ int hist[NBUCK];
    __shared__ int base[NBUCK];
    __shared__ int rank[NBUCK];
    int tid = threadIdx.x;
    for (int b = tid; b < NBUCK; b += 256) { hist[b] = 0; rank[b] = 0; }
    __syncthreads();
    int e0 = blockIdx.x * EPB_BIN;
#pragma unroll 4
    for (int k = 0; k < 32; k++) {
        int e = e0 + tid + k * 256;
        if (e < N_EDGES) atomicAdd(&hist[dst[e] >> 7], 1);
    }
    __syncthreads();
    for (int b = tid; b < NBUCK; b += 256) {
        int c = hist[b];
        base[b] = c ? atomicAdd(&bucket_cnt[b], c) : 0;
    }
    __syncthreads();
#pragma unroll 4
    for (int k = 0; k < 32; k++) {
        int e = e0 + tid + k * 256;
        if (e < N_EDGES) {
            int s = src[e], d = dst[e];
            float wv = w[e];
            int b = d >> 7;
            int r = atomicAdd(&rank[b], 1);
            int pos = base[b] + r;
            if (pos < BCAP) {
                ebuf[(size_t)b * BCAP + pos] =
                    make_uint2(((uint)(d & 127) << 17) | (uint)s, __float_as_uint(wv));
            } else {
                int oi = atomicAdd(spill_cnt, 1);
                if (oi < SPILL_MAX) sp[oi] = make_int4(s, d, __float_as_int(wv), 0);
            }
        }
    }
}

// per-bucket weighted degree -> dinv (dense write, LDS accumulate)
__global__ __launch_bounds__(256) void k_deg(const uint2* __restrict__ ebuf,
                                             const int* __restrict__ bucket_cnt,
                                             const int4* __restrict__ sp,
                                             const int* __restrict__ spill_cnt,
                                             float* __restrict__ dinv) {
    __shared__ float acc[BNODES];
    int b = blockIdx.x, tid = threadIdx.x;
    int lo = b * BNODES;
    int n = N_NODES - lo; if (n > BNODES) n = BNODES;
    if (tid < BNODES) acc[tid] = 0.0f;
    __syncthreads();
    int cnt = bucket_cnt[b]; if (cnt > BCAP) cnt = BCAP;
    const uint2* row = ebuf + (size_t)b * BCAP;
    for (int j = tid; j < cnt; j += 256) {
        uint2 u = row[j];
        atomicAdd(&acc[u.x >> 17], __uint_as_float(u.y));
    }
    int ns = *spill_cnt; if (ns > SPILL_MAX) ns = SPILL_MAX;
    for (int i = tid; i < ns; i += 256) {
        int4 q = sp[i];
        if ((q.y >> 7) == b) atomicAdd(&acc[q.y & 127], __int_as_float(q.z));
    }
    __syncthreads();
    if (tid < n) dinv[lo + tid] = rsqrtf(1.0f + acc[tid]);
}

// layer-1 aggregate (LDS) + per-node MLP -> h2, out init (self + bias included)
__global__ __launch_bounds__(256) void k_agg1_mlp(const uint2* __restrict__ ebuf,
                                                  const int* __restrict__ bucket_cnt,
                                                  const int4* __restrict__ sp,
                                                  const int* __restrict__ spill_cnt,
                                                  const float* __restrict__ dinv,
                                                  const float* __restrict__ x,
                                                  const float* __restrict__ W1,
                                                  const float* __restrict__ b1,
                                                  const float* __restrict__ W2,
                                                  const float* __restrict__ b2,
                                                  float* __restrict__ h2,
                                                  float* __restrict__ out) {
    __shared__ float acc[BNODES][16];       // 8 KB
    __shared__ float o1s[4][128];           // 2 KB
    int b = blockIdx.x, tid = threadIdx.x;
    int lo = b * BNODES;
    int n = N_NODES - lo; if (n > BNODES) n = BNODES;
    // seed with self-loop term: acc[nl][c] = dinv[node] * x[node][c]
    for (int t = tid; t < BNODES * 16; t += 256) {
        int nl = t >> 4, c = t & 15;
        acc[nl][c] = (nl < n) ? dinv[lo + nl] * x[(size_t)(lo + nl) * 16 + c] : 0.0f;
    }
    __syncthreads();
    int cnt = bucket_cnt[b]; if (cnt > BCAP) cnt = BCAP;
    const uint2* row = ebuf + (size_t)b * BCAP;
    int c = tid & 15, slot = tid >> 4;
    for (int j = slot; j < cnt; j += 16) {
        uint2 u = row[j];
        int s = u.x & 0x1FFFF;
        int nl = u.x >> 17;
        float f = dinv[s] * __uint_as_float(u.y);
        atomicAdd(&acc[nl][c], f * x[(size_t)s * 16 + c]);
    }
    int ns = *spill_cnt; if (ns > SPILL_MAX) ns = SPILL_MAX;
    for (int i = slot; i < ns; i += 16) {
        int4 q = sp[i];
        if ((q.y >> 7) == b) {
            float f = dinv[q.x] * __int_as_float(q.z);
            atomicAdd(&acc[q.y & 127][c], f * x[(size_t)q.x * 16 + c]);
        }
    }
    __syncthreads();
    // MLP: wave per node, 32 iterations cover 128 nodes
    int wave = tid >> 6, lane = tid & 63;
    int cc = lane & 15, g = lane >> 4;
    for (int it = 0; it < 32; it++) {
        int nl = it * 4 + wave;
        int node = lo + nl;
        float di = (nl < n) ? dinv[node] : 0.0f;
        float fv[16];
#pragma unroll
        for (int k = 0; k < 16; k++) fv[k] = acc[nl][k] * di;
        float a = b1[2 * lane], bb = b1[2 * lane + 1];
#pragma unroll
        for (int k = 0; k < 16; k++) {
            float2 wv = *(const float2*)(W1 + k * 128 + 2 * lane);
            a = fmaf(fv[k], wv.x, a);
            bb = fmaf(fv[k], wv.y, bb);
        }
        o1s[wave][2 * lane + 0] = fmaxf(a, 0.0f);
        o1s[wave][2 * lane + 1] = fmaxf(bb, 0.0f);   // same-wave LDS: no barrier needed
        float p = 0.0f;
#pragma unroll
        for (int k = 0; k < 32; k++) {
            int kk = g * 32 + k;
            p = fmaf(o1s[wave][kk], W2[kk * 16 + cc], p);
        }
        p += __shfl_down(p, 16, 64);
        p += __shfl_down(p, 32, 64);
        if (lane < 16 && nl < n) {
            h2[(size_t)node * 16 + cc] = p;
            out[(size_t)node * 16 + cc] = di * di * p + b2[cc];
        }
    }
}

// layer-2 aggregate (LDS) : out[node][c] += dinv_d * sum(dinv_s * w * h2[s][c])
__global__ __launch_bounds__(256) void k_agg2(const uint2* __restrict__ ebuf,
                                              const int* __restrict__ bucket_cnt,
                                              const int4* __restrict__ sp,
                                              const int* __restrict__ spill_cnt,
                                              const float* __restrict__ dinv,
                                              const float* __restrict__ h2,
                                              float* __restrict__ out) {
    __shared__ float acc[BNODES][16];
    int b = blockIdx.x, tid = threadIdx.x;
    int lo = b * BNODES;
    int n = N_NODES - lo; if (n > BNODES) n = BNODES;
    for (int t = tid; t < BNODES * 16; t += 256) acc[t >> 4][t & 15] = 0.0f;
    __syncthreads();
    int cnt = bucket_cnt[b]; if (cnt > BCAP) cnt = BCAP;
    const uint2* row = ebuf + (size_t)b * BCAP;
    int c = tid & 15, slot = tid >> 4;
    for (int j = slot; j < cnt; j += 16) {
        uint2 u = row[j];
        int s = u.x & 0x1FFFF;
        int nl = u.x >> 17;
        float f = dinv[s] * __uint_as_float(u.y);
        atomicAdd(&acc[nl][c], f * h2[(size_t)s * 16 + c]);
    }
    int ns = *spill_cnt; if (ns > SPILL_MAX) ns = SPILL_MAX;
    for (int i = slot; i < ns; i += 16) {
        int4 q = sp[i];
        if ((q.y >> 7) == b) {
            float f = dinv[q.x] * __int_as_float(q.z);
            atomicAdd(&acc[q.y & 127][c], f * h2[(size_t)q.x * 16 + c]);
        }
    }
    __syncthreads();
    for (int t = tid; t < BNODES * 16; t += 256) {
        int nl = t >> 4, cc = t & 15;
        if (nl < n) {
            int node = lo + nl;
            out[(size_t)node * 16 + cc] += dinv[node] * acc[nl][cc];
        }
    }
}

// ===================== CSR fallback (round-2) =====================

__global__ void k_init(float* __restrict__ deg, int* __restrict__ cnt) {
    int i = blockIdx.x * blockDim.x + threadIdx.x;
    if (i < N_NODES) { deg[i] = 1.0f; if (cnt) cnt[i] = 0; }
}

__global__ void k_degcnt(const int* __restrict__ dst, const float* __restrict__ w,
                         float* __restrict__ deg, int* __restrict__ cnt) {
    int e = blockIdx.x * blockDim.x + threadIdx.x;
    if (e < N_EDGES) {
        int d = dst[e];
        atomicAdd(&deg[d], w[e]);
        if (cnt) atomicAdd(&cnt[d], 1);
    }
}

__global__ void k_dinv_agg(const float* __restrict__ x, float* __restrict__ deg_dinv,
                           float* __restrict__ agg) {
    int i = blockIdx.x * blockDim.x + threadIdx.x;
    if (i >= N_NODES) return;
    float di = rsqrtf(deg_dinv[i]);
    deg_dinv[i] = di;
    float s = di * di;
    const float4* xr = (const float4*)(x + (size_t)i * 16);
    float4* ar = (float4*)(agg + (size_t)i * 16);
#pragma unroll
    for (int k = 0; k < 4; k++) {
        float4 v = xr[k];
        v.x *= s; v.y *= s; v.z *= s; v.w *= s;
        ar[k] = v;
    }
}

__global__ __launch_bounds__(256) void k_scan1(const int* __restrict__ cnt,
                                               int* __restrict__ rowptr,
                                               int* __restrict__ bsum) {
    __shared__ int ts[256];
    int tid = threadIdx.x;
    int base = blockIdx.x * SCAN_CHUNK + tid * 8;
    int v[8]; int s = 0;
#pragma unroll
    for (int k = 0; k < 8; k++) {
        int idx = base + k;
        v[k] = (idx < N_NODES) ? cnt[idx] : 0;
        s += v[k];
    }
    ts[tid] = s;
    __syncthreads();
    for (int off = 1; off < 256; off <<= 1) {
        int t = (tid >= off) ? ts[tid - off] : 0;
        __syncthreads();
        ts[tid] += t;
        __syncthreads();
    }
    int run = ts[tid] - s;
#pragma unroll
    for (int k = 0; k < 8; k++) {
        int idx = base + k;
        if (idx < N_NODES) rowptr[idx] = run;
        run += v[k];
    }
    if (tid == 255) bsum[blockIdx.x] = ts[255];
}

__global__ void k_scan2(int* __restrict__ bsum) {
    if (threadIdx.x == 0 && blockIdx.x == 0) {
        int run = 0;
        for (int g = 0; g < SCAN_BLOCKS; g++) { int t = bsum[g]; bsum[g] = run; run += t; }
    }
}

__global__ __launch_bounds__(256) void k_scan3(int* __restrict__ rowptr,
                                               const int* __restrict__ bsum) {
    int tid = threadIdx.x;
    int base = blockIdx.x * SCAN_CHUNK + tid * 8;
    int off = bsum[blockIdx.x];
#pragma unroll
    for (int k = 0; k < 8; k++) {
        int idx = base + k;
        if (idx < N_NODES) rowptr[idx] += off;
    }
    if (blockIdx.x == 0 && tid == 0) rowptr[N_NODES] = N_EDGES;
}

__global__ void k_fill(const int* __restrict__ src, const int* __restrict__ dst,
                       const float* __restrict__ w, const float* __restrict__ dinv,
                       const int* __restrict__ rowptr, int* __restrict__ cnt,
                       int2* __restrict__ perm) {
    int e = blockIdx.x * blockDim.x + threadIdx.x;
    if (e >= N_EDGES) return;
    int s = src[e], d = dst[e];
    float nrm = dinv[s] * w[e] * dinv[d];
    int r = atomicSub(&cnt[d], 1) - 1;
    int pos = rowptr[d] + r;
    perm[pos] = make_int2(s, __float_as_int(nrm));
}

__global__ __launch_bounds__(256) void k_gather(const int2* __restrict__ perm,
                                                const int* __restrict__ rowptr,
                                                const float* __restrict__ feat,
                                                float* __restrict__ out) {
    int wave = threadIdx.x >> 6, lane = threadIdx.x & 63;
    int node = blockIdx.x * 4 + wave;
    int c = lane & 15, eo = lane >> 4;
    int beg = rowptr[node], end = rowptr[node + 1];
    float acc = 0.0f;
    for (int j = beg + eo; j < end; j += 4) {
        int2 ed = perm[j];
        acc = fmaf(__int_as_float(ed.y), feat[(size_t)ed.x * 16 + c], acc);
    }
    acc += __shfl_xor(acc, 16, 64);
    acc += __shfl_xor(acc, 32, 64);
    if (lane < 16) out[(size_t)node * 16 + c] += acc;
}

__global__ __launch_bounds__(256) void k_mlp(float* __restrict__ agg,
                                             const float* __restrict__ W1,
                                             const float* __restrict__ b1,
                                             const float* __restrict__ W2,
                                             const float* __restrict__ b2,
                                             const float* __restrict__ dinv,
                                             float* __restrict__ out) {
    __shared__ float o1s[4][128];
    int wave = threadIdx.x >> 6;
    int lane = threadIdx.x & 63;
    int node = blockIdx.x * 4 + wave;
    const float* f = agg + (size_t)node * 16;
    float fv[16];
#pragma unroll
    for (int k = 0; k < 4; k++) {
        float4 v = ((const float4*)f)[k];
        fv[4 * k + 0] = v.x; fv[4 * k + 1] = v.y; fv[4 * k + 2] = v.z; fv[4 * k + 3] = v.w;
    }
    float a = b1[2 * lane], b = b1[2 * lane + 1];
#pragma unroll
    for (int k = 0; k < 16; k++) {
        float2 wv = *(const float2*)(W1 + k * 128 + 2 * lane);
        a = fmaf(fv[k], wv.x, a);
        b = fmaf(fv[k], wv.y, b);
    }
    o1s[wave][2 * lane + 0] = fmaxf(a, 0.0f);
    o1s[wave][2 * lane + 1] = fmaxf(b, 0.0f);
    __syncthreads();
    int c = lane & 15, g = lane >> 4;
    float p = 0.0f;
#pragma unroll
    for (int k = 0; k < 32; k++) {
        int kk = g * 32 + k;
        p = fmaf(o1s[wave][kk], W2[kk * 16 + c], p);
    }
    p += __shfl_down(p, 16, 64);
    p += __shfl_down(p, 32, 64);
    __syncthreads();
    if (lane < 16) {
        float h2v = p;
        agg[(size_t)node * 16 + c] = h2v;
        float di = dinv[node];
        out[(size_t)node * 16 + c] = di * di * h2v + b2[c];
    }
}

__global__ void k_scatter(const int* __restrict__ src, const int* __restrict__ dst,
                          const float* __restrict__ w, const float* __restrict__ dinv,
                          const float* __restrict__ feat, float* __restrict__ out) {
    int t = blockIdx.x * blockDim.x + threadIdx.x;
    int e = t >> 2;
    int c4 = (t & 3) * 4;
    if (e >= N_EDGES) return;
    int s = src[e], d = dst[e];
    float nrm = dinv[s] * w[e] * dinv[d];
    float4 v = *(const float4*)(feat + (size_t)s * 16 + c4);
    float* o = out + (size_t)d * 16 + c4;
    atomicAdd(o + 0, nrm * v.x);
    atomicAdd(o + 1, nrm * v.y);
    atomicAdd(o + 2, nrm * v.z);
    atomicAdd(o + 3, nrm * v.w);
}

// ===================== launch =====================

extern "C" void kernel_launch(void* const* d_in, const int* in_sizes, int n_in,
                              void* d_out, int out_size, void* d_ws, size_t ws_size,
                              hipStream_t stream) {
    const float* x  = (const float*)d_in[0];
    const int*   ei = (const int*)d_in[1];
    const float* w  = (const float*)d_in[2];
    const float* W1 = (const float*)d_in[3];
    const float* b1 = (const float*)d_in[4];
    const float* W2 = (const float*)d_in[5];
    const float* b2 = (const float*)d_in[6];
    float* out = (float*)d_out;

    const int* src = ei;
    const int* dst = ei + N_EDGES;
    const int B = 256;

    // ---- bucket workspace layout (16B-aligned blocks) ----
    char* p = (char*)d_ws;
    int*   bucket_cnt = (int*)p;           p += (size_t)((NBUCK + 3) & ~3) * 4;
    int*   spill_cnt  = (int*)p;           p += 16;
    float* dinv       = (float*)p;         p += (size_t)N_PAD * 4;
    float* h2         = (float*)p;         p += (size_t)N_NODES * 16 * 4;
    int4*  sp         = (int4*)p;          p += (size_t)SPILL_MAX * 16;
    uint2* ebuf       = (uint2*)p;         p += (size_t)NBUCK * BCAP * 8;
    const size_t WS_BKT = (size_t)(p - (char*)d_ws);

    if (ws_size >= WS_BKT) {
        k_zero<<<(NBUCK + B - 1) / B, B, 0, stream>>>(bucket_cnt, spill_cnt);
        k_bin<<<BIN_BLOCKS, B, 0, stream>>>(src, dst, w, bucket_cnt, ebuf, sp, spill_cnt);
        k_deg<<<NBUCK, B, 0, stream>>>(ebuf, bucket_cnt, sp, spill_cnt, dinv);
        k_agg1_mlp<<<NBUCK, B, 0, stream>>>(ebuf, bucket_cnt, sp, spill_cnt, dinv, x,
                                            W1, b1, W2, b2, h2, out);
        k_agg2<<<NBUCK, B, 0, stream>>>(ebuf, bucket_cnt, sp, spill_cnt, dinv, h2, out);
        return;
    }

    // ---- CSR fallback (round-2 path) ----
    float* deg_dinv = (float*)d_ws;
    int*   cnt      = (int*)(deg_dinv + N_PAD);
    int*   rowptr   = cnt + N_PAD;
    int*   bsum     = rowptr + N_PAD;
    float* agg      = (float*)(bsum + 64);
    int2*  perm     = (int2*)(agg + (size_t)N_NODES * 16);
    const size_t WS_CSR = ((size_t)N_PAD * 3 + 64 + (size_t)N_NODES * 16) * 4
                          + (size_t)N_EDGES * 8;

    if (ws_size >= WS_CSR) {
        k_init<<<(N_NODES + B - 1) / B, B, 0, stream>>>(deg_dinv, cnt);
        k_degcnt<<<(N_EDGES + B - 1) / B, B, 0, stream>>>(dst, w, deg_dinv, cnt);
        k_dinv_agg<<<(N_NODES + B - 1) / B, B, 0, stream>>>(x, deg_dinv, agg);
        k_scan1<<<SCAN_BLOCKS, 256, 0, stream>>>(cnt, rowptr, bsum);
        k_scan2<<<1, 64, 0, stream>>>(bsum);
        k_scan3<<<SCAN_BLOCKS, 256, 0, stream>>>(rowptr, bsum);
        k_fill<<<(N_EDGES + B - 1) / B, B, 0, stream>>>(src, dst, w, deg_dinv,
                                                        rowptr, cnt, perm);
        k_gather<<<N_NODES / 4, B, 0, stream>>>(perm, rowptr, x, agg);
        k_mlp<<<N_NODES / 4, B, 0, stream>>>(agg, W1, b1, W2, b2, deg_dinv, out);
        k_gather<<<N_NODES / 4, B, 0, stream>>>(perm, rowptr, agg, out);
    } else {
        float* deg = (float*)d_ws;
        float* ag  = (float*)d_ws + N_NODES;
        k_init<<<(N_NODES + B - 1) / B, B, 0, stream>>>(deg, (int*)nullptr);
        k_degcnt<<<(N_EDGES + B - 1) / B, B, 0, stream>>>(dst, w, deg, (int*)nullptr);
        k_dinv_agg<<<(N_NODES + B - 1) / B, B, 0, stream>>>(x, deg, ag);
        k_scatter<<<((size_t)N_EDGES * 4 + B - 1) / B, B, 0, stream>>>(src, dst, w, deg, x, ag);
        k_mlp<<<N_NODES / 4, B, 0, stream>>>(ag, W1, b1, W2, b2, deg, out);
        k_scatter<<<((size_t)N_EDGES * 4 + B - 1) / B, B, 0, stream>>>(src, dst, w, deg, ag, out);
    }
}

// Round 7
// 488.825 us; speedup vs baseline: 1.7905x; 1.7905x over previous
//
#include <hip/hip_runtime.h>
#include <hip/hip_fp16.h>

#define N_NODES 100000
#define N_EDGES 3200000
#define N_PAD   100096
#define BNODES  128
#define NBUCK   ((N_NODES + BNODES - 1) / BNODES)       // 782
#define BCAP    4800                                    // mean 4096, sigma 64 (11 sigma)
#define EPB_BIN 4096                                    // edges per bin block (16/thread)
#define BIN_BLOCKS ((N_EDGES + EPB_BIN - 1) / EPB_BIN)  // 782
#define SPILL_MAX 65536
#define WQSCALE  32767.0f
#define SCAN_CHUNK 2048
#define SCAN_BLOCKS ((N_NODES + SCAN_CHUNK - 1) / SCAN_CHUNK)

typedef unsigned int uint;

// ===================== fast path: bin -> sort -> gather =====================

// prologue: x -> fp16, zero bucket_cnt/spill_cnt
__global__ __launch_bounds__(256) void k_pre(const float* __restrict__ x,
                                             __half* __restrict__ x16,
                                             int* __restrict__ bucket_cnt,
                                             int* __restrict__ spill_cnt) {
    int i = blockIdx.x * blockDim.x + threadIdx.x;
    if (i < N_NODES * 16) x16[i] = __float2half(x[i]);
    if (i < NBUCK) bucket_cnt[i] = 0;
    if (i == 0) *spill_cnt = 0;
}

// counting-sort edges into 782 dst-buckets; entry = { (dstl<<17)|src , w_bits }
__global__ __launch_bounds__(256) void k_bin(const int* __restrict__ src,
                                             const int* __restrict__ dst,
                                             const float* __restrict__ w,
                                             int* __restrict__ bucket_cnt,
                                             uint2* __restrict__ ebuf,
                                             int4* __restrict__ sp,
                                             int* __restrict__ spill_cnt) {
    __shared__ int hist[NBUCK];
    __shared__ int base[NBUCK];
    __shared__ int rank[NBUCK];
    int tid = threadIdx.x;
    for (int b = tid; b < NBUCK; b += 256) { hist[b] = 0; rank[b] = 0; }
    __syncthreads();
    int e0 = blockIdx.x * EPB_BIN;
#pragma unroll 4
    for (int k = 0; k < 16; k++) {
        int e = e0 + tid + k * 256;
        if (e < N_EDGES) atomicAdd(&hist[__builtin_nontemporal_load(dst + e) >> 7], 1);
    }
    __syncthreads();
    for (int b = tid; b < NBUCK; b += 256) {
        int c = hist[b];
        base[b] = c ? atomicAdd(&bucket_cnt[b], c) : 0;
    }
    __syncthreads();
#pragma unroll 4
    for (int k = 0; k < 16; k++) {
        int e = e0 + tid + k * 256;
        if (e < N_EDGES) {
            int s = __builtin_nontemporal_load(src + e);
            int d = __builtin_nontemporal_load(dst + e);
            float wv = __builtin_nontemporal_load(w + e);
            int b = d >> 7;
            int r = atomicAdd(&rank[b], 1);
            int pos = base[b] + r;
            if (pos < BCAP) {
                ebuf[(size_t)b * BCAP + pos] =
                    make_uint2(((uint)(d & 127) << 17) | (uint)s, __float_as_uint(wv));
            } else {
                int oi = atomicAdd(spill_cnt, 1);
                if (oi < SPILL_MAX) sp[oi] = make_int4(s, d, __float_as_int(wv), 0);
            }
        }
    }
}

// per-bucket: stage in LDS, node-histogram + weighted degree, prefix, scatter to
// node-major 4B entries (overlaying the bucket's own ebuf region), write dinv/rowptr.
__global__ __launch_bounds__(256) void k_sort(uint2* __restrict__ ebuf,
                                              const int* __restrict__ bucket_cnt,
                                              const int4* __restrict__ sp,
                                              const int* __restrict__ spill_cnt,
                                              float* __restrict__ dinv,
                                              int* __restrict__ row_beg,
                                              int* __restrict__ row_cnt) {
    __shared__ uint2 ent[BCAP];          // 38.4 KB
    __shared__ float wacc[BNODES];
    __shared__ int   hist[BNODES];
    __shared__ int   pref[BNODES];
    __shared__ int   curs[BNODES];
    int b = blockIdx.x, tid = threadIdx.x;
    int lo = b * BNODES;
    int n = N_NODES - lo; if (n > BNODES) n = BNODES;
    if (tid < BNODES) { wacc[tid] = 0.0f; hist[tid] = 0; }
    __syncthreads();
    int cnt = bucket_cnt[b]; if (cnt > BCAP) cnt = BCAP;
    const uint2* srcrow = ebuf + (size_t)b * BCAP;
    for (int j = tid; j < cnt; j += 256) {
        uint2 e = srcrow[j];
        ent[j] = e;
        int nl = e.x >> 17;
        atomicAdd(&hist[nl], 1);
        atomicAdd(&wacc[nl], __uint_as_float(e.y));
    }
    int ns = *spill_cnt; if (ns > SPILL_MAX) ns = SPILL_MAX;
    for (int i = tid; i < ns; i += 256) {
        int4 q = sp[i];
        if ((q.y >> 7) == b) atomicAdd(&wacc[q.y & 127], __int_as_float(q.z));
    }
    __syncthreads();
    // inclusive prefix over hist -> pref
    if (tid < BNODES) pref[tid] = hist[tid];
    __syncthreads();
    for (int off = 1; off < BNODES; off <<= 1) {
        int v = 0;
        if (tid < BNODES && tid >= off) v = pref[tid - off];
        __syncthreads();
        if (tid < BNODES) pref[tid] += v;
        __syncthreads();
    }
    if (tid < BNODES) curs[tid] = pref[tid] - hist[tid];   // exclusive start
    if (tid < n) {
        row_beg[lo + tid] = b * (BCAP * 2) + (pref[tid] - hist[tid]);
        row_cnt[lo + tid] = hist[tid];
        dinv[lo + tid] = rsqrtf(1.0f + wacc[tid]);
    }
    __syncthreads();
    // scatter node-sorted 4B entries over the bucket's own region (source is in LDS)
    uint* outb = (uint*)ebuf + (size_t)b * (BCAP * 2);
    for (int j = tid; j < cnt; j += 256) {
        uint2 e = ent[j];
        int nl = e.x >> 17;
        int pos = atomicAdd(&curs[nl], 1);
        uint wq = __float2uint_rn(__uint_as_float(e.y) * WQSCALE);
        outb[pos] = (wq << 17) | (e.x & 0x1FFFF);
    }
}

// fused: layer-1 gather (fp16 x) + self term + MLP -> h2 (fp16), out init.
// wave per node; 64 lanes = 4 edge-slots x 16 channels.
__global__ __launch_bounds__(256) void k_gather_mlp(const uint* __restrict__ sbuf,
                                                    const int* __restrict__ row_beg,
                                                    const int* __restrict__ row_cnt,
                                                    const int4* __restrict__ sp,
                                                    const int* __restrict__ spill_cnt,
                                                    const float* __restrict__ dinv,
                                                    const __half* __restrict__ x16,
                                                    const float* __restrict__ W1,
                                                    const float* __restrict__ b1,
                                                    const float* __restrict__ W2,
                                                    const float* __restrict__ b2,
                                                    __half* __restrict__ h2,
                                                    float* __restrict__ out) {
    __shared__ float fvs[4][16];
    __shared__ float o1s[4][128];
    int wave = threadIdx.x >> 6, lane = threadIdx.x & 63;
    int node = blockIdx.x * 4 + wave;            // N_NODES % 4 == 0
    int c = lane & 15, eo = lane >> 4;
    int beg = row_beg[node], cnt = row_cnt[node];
    float di = dinv[node];
    const uint* row = sbuf + beg;
    float acc = 0.0f;
    for (int j = eo; j < cnt; j += 4) {
        uint e = __builtin_nontemporal_load(row + j);
        int s = e & 0x1FFFF;
        float wv = (float)(e >> 17) * (1.0f / WQSCALE);
        float nrm = dinv[s] * wv * di;
        acc = fmaf(nrm, __half2float(x16[(size_t)s * 16 + c]), acc);
    }
    acc += __shfl_xor(acc, 16, 64);
    acc += __shfl_xor(acc, 32, 64);
    acc += di * di * __half2float(x16[(size_t)node * 16 + c]);
    int ns = *spill_cnt;                         // 0 in practice
    if (ns > 0) {
        if (ns > SPILL_MAX) ns = SPILL_MAX;
        for (int i = 0; i < ns; i++) {
            int4 q = sp[i];
            if (q.y == node)
                acc += dinv[q.x] * __int_as_float(q.z) * di *
                       __half2float(x16[(size_t)q.x * 16 + c]);
        }
    }
    if (lane < 16) fvs[wave][c] = acc;
    __syncthreads();
    float fv[16];
#pragma unroll
    for (int k = 0; k < 16; k++) fv[k] = fvs[wave][k];
    float a = b1[2 * lane], bb = b1[2 * lane + 1];
#pragma unroll
    for (int k = 0; k < 16; k++) {
        float2 wv = *(const float2*)(W1 + k * 128 + 2 * lane);
        a = fmaf(fv[k], wv.x, a);
        bb = fmaf(fv[k], wv.y, bb);
    }
    o1s[wave][2 * lane + 0] = fmaxf(a, 0.0f);
    o1s[wave][2 * lane + 1] = fmaxf(bb, 0.0f);
    __syncthreads();
    int g = lane >> 4;
    float p = 0.0f;
#pragma unroll
    for (int k = 0; k < 32; k++) {
        int kk = g * 32 + k;
        p = fmaf(o1s[wave][kk], W2[kk * 16 + c], p);
    }
    p += __shfl_down(p, 16, 64);
    p += __shfl_down(p, 32, 64);
    if (lane < 16) {
        h2[(size_t)node * 16 + c] = __float2half(p);
        out[(size_t)node * 16 + c] = di * di * p + b2[c];
    }
}

// layer-2 gather: out[node][c] += sum nrm * h2[src][c]
__global__ __launch_bounds__(256) void k_gather2(const uint* __restrict__ sbuf,
                                                 const int* __restrict__ row_beg,
                                                 const int* __restrict__ row_cnt,
                                                 const int4* __restrict__ sp,
                                                 const int* __restrict__ spill_cnt,
                                                 const float* __restrict__ dinv,
                                                 const __half* __restrict__ h2,
                                                 float* __restrict__ out) {
    int wave = threadIdx.x >> 6, lane = threadIdx.x & 63;
    int node = blockIdx.x * 4 + wave;
    int c = lane & 15, eo = lane >> 4;
    int beg = row_beg[node], cnt = row_cnt[node];
    float di = dinv[node];
    const uint* row = sbuf + beg;
    float acc = 0.0f;
    for (int j = eo; j < cnt; j += 4) {
        uint e = __builtin_nontemporal_load(row + j);
        int s = e & 0x1FFFF;
        float wv = (float)(e >> 17) * (1.0f / WQSCALE);
        float nrm = dinv[s] * wv * di;
        acc = fmaf(nrm, __half2float(h2[(size_t)s * 16 + c]), acc);
    }
    acc += __shfl_xor(acc, 16, 64);
    acc += __shfl_xor(acc, 32, 64);
    int ns = *spill_cnt;
    if (ns > 0) {
        if (ns > SPILL_MAX) ns = SPILL_MAX;
        for (int i = 0; i < ns; i++) {
            int4 q = sp[i];
            if (q.y == node)
                acc += dinv[q.x] * __int_as_float(q.z) * di *
                       __half2float(h2[(size_t)q.x * 16 + c]);
        }
    }
    if (lane < 16) out[(size_t)node * 16 + c] += acc;
}

// ===================== CSR fallback (round-2) =====================

__global__ void k_init(float* __restrict__ deg, int* __restrict__ cnt) {
    int i = blockIdx.x * blockDim.x + threadIdx.x;
    if (i < N_NODES) { deg[i] = 1.0f; if (cnt) cnt[i] = 0; }
}

__global__ void k_degcnt(const int* __restrict__ dst, const float* __restrict__ w,
                         float* __restrict__ deg, int* __restrict__ cnt) {
    int e = blockIdx.x * blockDim.x + threadIdx.x;
    if (e < N_EDGES) {
        int d = dst[e];
        atomicAdd(&deg[d], w[e]);
        if (cnt) atomicAdd(&cnt[d], 1);
    }
}

__global__ void k_dinv_agg(const float* __restrict__ x, float* __restrict__ deg_dinv,
                           float* __restrict__ agg) {
    int i = blockIdx.x * blockDim.x + threadIdx.x;
    if (i >= N_NODES) return;
    float di = rsqrtf(deg_dinv[i]);
    deg_dinv[i] = di;
    float s = di * di;
    const float4* xr = (const float4*)(x + (size_t)i * 16);
    float4* ar = (float4*)(agg + (size_t)i * 16);
#pragma unroll
    for (int k = 0; k < 4; k++) {
        float4 v = xr[k];
        v.x *= s; v.y *= s; v.z *= s; v.w *= s;
        ar[k] = v;
    }
}

__global__ __launch_bounds__(256) void k_scan1(const int* __restrict__ cnt,
                                               int* __restrict__ rowptr,
                                               int* __restrict__ bsum) {
    __shared__ int ts[256];
    int tid = threadIdx.x;
    int base = blockIdx.x * SCAN_CHUNK + tid * 8;
    int v[8]; int s = 0;
#pragma unroll
    for (int k = 0; k < 8; k++) {
        int idx = base + k;
        v[k] = (idx < N_NODES) ? cnt[idx] : 0;
        s += v[k];
    }
    ts[tid] = s;
    __syncthreads();
    for (int off = 1; off < 256; off <<= 1) {
        int t = (tid >= off) ? ts[tid - off] : 0;
        __syncthreads();
        ts[tid] += t;
        __syncthreads();
    }
    int run = ts[tid] - s;
#pragma unroll
    for (int k = 0; k < 8; k++) {
        int idx = base + k;
        if (idx < N_NODES) rowptr[idx] = run;
        run += v[k];
    }
    if (tid == 255) bsum[blockIdx.x] = ts[255];
}

__global__ void k_scan2(int* __restrict__ bsum) {
    if (threadIdx.x == 0 && blockIdx.x == 0) {
        int run = 0;
        for (int g = 0; g < SCAN_BLOCKS; g++) { int t = bsum[g]; bsum[g] = run; run += t; }
    }
}

__global__ __launch_bounds__(256) void k_scan3(int* __restrict__ rowptr,
                                               const int* __restrict__ bsum) {
    int tid = threadIdx.x;
    int base = blockIdx.x * SCAN_CHUNK + tid * 8;
    int off = bsum[blockIdx.x];
#pragma unroll
    for (int k = 0; k < 8; k++) {
        int idx = base + k;
        if (idx < N_NODES) rowptr[idx] += off;
    }
    if (blockIdx.x == 0 && tid == 0) rowptr[N_NODES] = N_EDGES;
}

__global__ void k_fill(const int* __restrict__ src, const int* __restrict__ dst,
                       const float* __restrict__ w, const float* __restrict__ dinv,
                       const int* __restrict__ rowptr, int* __restrict__ cnt,
                       int2* __restrict__ perm) {
    int e = blockIdx.x * blockDim.x + threadIdx.x;
    if (e >= N_EDGES) return;
    int s = src[e], d = dst[e];
    float nrm = dinv[s] * w[e] * dinv[d];
    int r = atomicSub(&cnt[d], 1) - 1;
    int pos = rowptr[d] + r;
    perm[pos] = make_int2(s, __float_as_int(nrm));
}

__global__ __launch_bounds__(256) void k_gather(const int2* __restrict__ perm,
                                                const int* __restrict__ rowptr,
                                                const float* __restrict__ feat,
                                                float* __restrict__ out) {
    int wave = threadIdx.x >> 6, lane = threadIdx.x & 63;
    int node = blockIdx.x * 4 + wave;
    int c = lane & 15, eo = lane >> 4;
    int beg = rowptr[node], end = rowptr[node + 1];
    float acc = 0.0f;
    for (int j = beg + eo; j < end; j += 4) {
        int2 ed = perm[j];
        acc = fmaf(__int_as_float(ed.y), feat[(size_t)ed.x * 16 + c], acc);
    }
    acc += __shfl_xor(acc, 16, 64);
    acc += __shfl_xor(acc, 32, 64);
    if (lane < 16) out[(size_t)node * 16 + c] += acc;
}

__global__ __launch_bounds__(256) void k_mlp(float* __restrict__ agg,
                                             const float* __restrict__ W1,
                                             const float* __restrict__ b1,
                                             const float* __restrict__ W2,
                                             const float* __restrict__ b2,
                                             const float* __restrict__ dinv,
                                             float* __restrict__ out) {
    __shared__ float o1s[4][128];
    int wave = threadIdx.x >> 6;
    int lane = threadIdx.x & 63;
    int node = blockIdx.x * 4 + wave;
    const float* f = agg + (size_t)node * 16;
    float fv[16];
#pragma unroll
    for (int k = 0; k < 4; k++) {
        float4 v = ((const float4*)f)[k];
        fv[4 * k + 0] = v.x; fv[4 * k + 1] = v.y; fv[4 * k + 2] = v.z; fv[4 * k + 3] = v.w;
    }
    float a = b1[2 * lane], b = b1[2 * lane + 1];
#pragma unroll
    for (int k = 0; k < 16; k++) {
        float2 wv = *(const float2*)(W1 + k * 128 + 2 * lane);
        a = fmaf(fv[k], wv.x, a);
        b = fmaf(fv[k], wv.y, b);
    }
    o1s[wave][2 * lane + 0] = fmaxf(a, 0.0f);
    o1s[wave][2 * lane + 1] = fmaxf(b, 0.0f);
    __syncthreads();
    int c = lane & 15, g = lane >> 4;
    float p = 0.0f;
#pragma unroll
    for (int k = 0; k < 32; k++) {
        int kk = g * 32 + k;
        p = fmaf(o1s[wave][kk], W2[kk * 16 + c], p);
    }
    p += __shfl_down(p, 16, 64);
    p += __shfl_down(p, 32, 64);
    __syncthreads();
    if (lane < 16) {
        float h2v = p;
        agg[(size_t)node * 16 + c] = h2v;
        float di = dinv[node];
        out[(size_t)node * 16 + c] = di * di * h2v + b2[c];
    }
}

__global__ void k_scatter(const int* __restrict__ src, const int* __restrict__ dst,
                          const float* __restrict__ w, const float* __restrict__ dinv,
                          const float* __restrict__ feat, float* __restrict__ out) {
    int t = blockIdx.x * blockDim.x + threadIdx.x;
    int e = t >> 2;
    int c4 = (t & 3) * 4;
    if (e >= N_EDGES) return;
    int s = src[e], d = dst[e];
    float nrm = dinv[s] * w[e] * dinv[d];
    float4 v = *(const float4*)(feat + (size_t)s * 16 + c4);
    float* o = out + (size_t)d * 16 + c4;
    atomicAdd(o + 0, nrm * v.x);
    atomicAdd(o + 1, nrm * v.y);
    atomicAdd(o + 2, nrm * v.z);
    atomicAdd(o + 3, nrm * v.w);
}

// ===================== launch =====================

extern "C" void kernel_launch(void* const* d_in, const int* in_sizes, int n_in,
                              void* d_out, int out_size, void* d_ws, size_t ws_size,
                              hipStream_t stream) {
    const float* x  = (const float*)d_in[0];
    const int*   ei = (const int*)d_in[1];
    const float* w  = (const float*)d_in[2];
    const float* W1 = (const float*)d_in[3];
    const float* b1 = (const float*)d_in[4];
    const float* W2 = (const float*)d_in[5];
    const float* b2 = (const float*)d_in[6];
    float* out = (float*)d_out;

    const int* src = ei;
    const int* dst = ei + N_EDGES;
    const int B = 256;

    // ---- fast-path workspace layout (16B-aligned blocks) ----
    char* p = (char*)d_ws;
    int*    bucket_cnt = (int*)p;        p += (size_t)((NBUCK + 3) & ~3) * 4;
    int*    spill_cnt  = (int*)p;        p += 16;
    float*  dinv       = (float*)p;      p += (size_t)N_PAD * 4;
    int*    row_beg    = (int*)p;        p += (size_t)N_PAD * 4;
    int*    row_cnt    = (int*)p;        p += (size_t)N_PAD * 4;
    __half* x16        = (__half*)p;     p += (size_t)N_NODES * 16 * 2;
    __half* h2         = (__half*)p;     p += (size_t)N_NODES * 16 * 2;
    int4*   sp         = (int4*)p;       p += (size_t)SPILL_MAX * 16;
    uint2*  ebuf       = (uint2*)p;      p += (size_t)NBUCK * BCAP * 8;
    const size_t WS_FAST = (size_t)(p - (char*)d_ws);

    if (ws_size >= WS_FAST) {
        k_pre<<<(N_NODES * 16 + B - 1) / B, B, 0, stream>>>(x, x16, bucket_cnt, spill_cnt);
        k_bin<<<BIN_BLOCKS, B, 0, stream>>>(src, dst, w, bucket_cnt, ebuf, sp, spill_cnt);
        k_sort<<<NBUCK, B, 0, stream>>>(ebuf, bucket_cnt, sp, spill_cnt,
                                        dinv, row_beg, row_cnt);
        k_gather_mlp<<<N_NODES / 4, B, 0, stream>>>((const uint*)ebuf, row_beg, row_cnt,
                                                    sp, spill_cnt, dinv, x16,
                                                    W1, b1, W2, b2, h2, out);
        k_gather2<<<N_NODES / 4, B, 0, stream>>>((const uint*)ebuf, row_beg, row_cnt,
                                                 sp, spill_cnt, dinv, h2, out);
        return;
    }

    // ---- CSR fallback (round-2 path) ----
    float* deg_dinv = (float*)d_ws;
    int*   cntb     = (int*)(deg_dinv + N_PAD);
    int*   rowptr   = cntb + N_PAD;
    int*   bsum     = rowptr + N_PAD;
    float* agg      = (float*)(bsum + 64);
    int2*  perm     = (int2*)(agg + (size_t)N_NODES * 16);
    const size_t WS_CSR = ((size_t)N_PAD * 3 + 64 + (size_t)N_NODES * 16) * 4
                          + (size_t)N_EDGES * 8;

    if (ws_size >= WS_CSR) {
        k_init<<<(N_NODES + B - 1) / B, B, 0, stream>>>(deg_dinv, cntb);
        k_degcnt<<<(N_EDGES + B - 1) / B, B, 0, stream>>>(dst, w, deg_dinv, cntb);
        k_dinv_agg<<<(N_NODES + B - 1) / B, B, 0, stream>>>(x, deg_dinv, agg);
        k_scan1<<<SCAN_BLOCKS, 256, 0, stream>>>(cntb, rowptr, bsum);
        k_scan2<<<1, 64, 0, stream>>>(bsum);
        k_scan3<<<SCAN_BLOCKS, 256, 0, stream>>>(rowptr, bsum);
        k_fill<<<(N_EDGES + B - 1) / B, B, 0, stream>>>(src, dst, w, deg_dinv,
                                                        rowptr, cntb, perm);
        k_gather<<<N_NODES / 4, B, 0, stream>>>(perm, rowptr, x, agg);
        k_mlp<<<N_NODES / 4, B, 0, stream>>>(agg, W1, b1, W2, b2, deg_dinv, out);
        k_gather<<<N_NODES / 4, B, 0, stream>>>(perm, rowptr, agg, out);
    } else {
        float* deg = (float*)d_ws;
        float* ag  = (float*)d_ws + N_NODES;
        k_init<<<(N_NODES + B - 1) / B, B, 0, stream>>>(deg, (int*)nullptr);
        k_degcnt<<<(N_EDGES + B - 1) / B, B, 0, stream>>>(dst, w, deg, (int*)nullptr);
        k_dinv_agg<<<(N_NODES + B - 1) / B, B, 0, stream>>>(x, deg, ag);
        k_scatter<<<((size_t)N_EDGES * 4 + B - 1) / B, B, 0, stream>>>(src, dst, w, deg, x, ag);
        k_mlp<<<N_NODES / 4, B, 0, stream>>>(ag, W1, b1, W2, b2, deg, out);
        k_scatter<<<((size_t)N_EDGES * 4 + B - 1) / B, B, 0, stream>>>(src, dst, w, deg, ag, out);
    }
}

// Round 8
// 390.174 us; speedup vs baseline: 2.2432x; 1.2528x over previous
//
#include <hip/hip_runtime.h>
#include <hip/hip_fp16.h>

#define N_NODES 100000
#define N_EDGES 3200000
#define N_PAD   100096
#define BNODES  128
#define NBUCK   ((N_NODES + BNODES - 1) / BNODES)       // 782
#define BCAP    4800                                    // mean 4096, sigma 64 (11 sigma)
#define EPB_BIN 4096                                    // edges per bin block (16/thread)
#define BIN_BLOCKS ((N_EDGES + EPB_BIN - 1) / EPB_BIN)  // 782
#define SPILL_MAX 65536
#define WQSCALE  32767.0f
#define NPX      (N_NODES / 8)                          // 12500 nodes per XCD slab
#define SCAN_CHUNK 2048
#define SCAN_BLOCKS ((N_NODES + SCAN_CHUNK - 1) / SCAN_CHUNK)

typedef unsigned int uint;

// ===================== fast path: bin -> sort -> nrm -> gather =====================

// prologue: x -> fp16, zero bucket_cnt/spill_cnt
__global__ __launch_bounds__(256) void k_pre(const float* __restrict__ x,
                                             __half* __restrict__ x16,
                                             int* __restrict__ bucket_cnt,
                                             int* __restrict__ spill_cnt) {
    int i = blockIdx.x * blockDim.x + threadIdx.x;
    if (i < N_NODES * 16) x16[i] = __float2half(x[i]);
    if (i < NBUCK) bucket_cnt[i] = 0;
    if (i == 0) *spill_cnt = 0;
}

// counting-sort edges into 782 dst-buckets; entry = { (dstl<<17)|src , w_bits }
__global__ __launch_bounds__(256) void k_bin(const int* __restrict__ src,
                                             const int* __restrict__ dst,
                                             const float* __restrict__ w,
                                             int* __restrict__ bucket_cnt,
                                             uint2* __restrict__ ebuf,
                                             int4* __restrict__ sp,
                                             int* __restrict__ spill_cnt) {
    __shared__ int hist[NBUCK];
    __shared__ int base[NBUCK];
    __shared__ int rank[NBUCK];
    int tid = threadIdx.x;
    for (int b = tid; b < NBUCK; b += 256) { hist[b] = 0; rank[b] = 0; }
    __syncthreads();
    int e0 = blockIdx.x * EPB_BIN;
#pragma unroll 4
    for (int k = 0; k < 16; k++) {
        int e = e0 + tid + k * 256;
        if (e < N_EDGES) atomicAdd(&hist[__builtin_nontemporal_load(dst + e) >> 7], 1);
    }
    __syncthreads();
    for (int b = tid; b < NBUCK; b += 256) {
        int c = hist[b];
        base[b] = c ? atomicAdd(&bucket_cnt[b], c) : 0;
    }
    __syncthreads();
#pragma unroll 4
    for (int k = 0; k < 16; k++) {
        int e = e0 + tid + k * 256;
        if (e < N_EDGES) {
            int s = __builtin_nontemporal_load(src + e);
            int d = __builtin_nontemporal_load(dst + e);
            float wv = __builtin_nontemporal_load(w + e);
            int b = d >> 7;
            int r = atomicAdd(&rank[b], 1);
            int pos = base[b] + r;
            if (pos < BCAP) {
                ebuf[(size_t)b * BCAP + pos] =
                    make_uint2(((uint)(d & 127) << 17) | (uint)s, __float_as_uint(wv));
            } else {
                int oi = atomicAdd(spill_cnt, 1);
                if (oi < SPILL_MAX) sp[oi] = make_int4(s, d, __float_as_int(wv), 0);
            }
        }
    }
}

// per-bucket: stage in LDS, node-histogram + weighted degree, prefix, scatter to
// node-major 4B entries (overlaying the bucket's own ebuf region), write dinv/rowptr.
__global__ __launch_bounds__(256) void k_sort(uint2* __restrict__ ebuf,
                                              const int* __restrict__ bucket_cnt,
                                              const int4* __restrict__ sp,
                                              const int* __restrict__ spill_cnt,
                                              float* __restrict__ dinv,
                                              int* __restrict__ row_beg,
                                              int* __restrict__ row_cnt) {
    __shared__ uint2 ent[BCAP];          // 38.4 KB
    __shared__ float wacc[BNODES];
    __shared__ int   hist[BNODES];
    __shared__ int   pref[BNODES];
    __shared__ int   curs[BNODES];
    int b = blockIdx.x, tid = threadIdx.x;
    int lo = b * BNODES;
    int n = N_NODES - lo; if (n > BNODES) n = BNODES;
    if (tid < BNODES) { wacc[tid] = 0.0f; hist[tid] = 0; }
    __syncthreads();
    int cnt = bucket_cnt[b]; if (cnt > BCAP) cnt = BCAP;
    const uint2* srcrow = ebuf + (size_t)b * BCAP;
    for (int j = tid; j < cnt; j += 256) {
        uint2 e = srcrow[j];
        ent[j] = e;
        int nl = e.x >> 17;
        atomicAdd(&hist[nl], 1);
        atomicAdd(&wacc[nl], __uint_as_float(e.y));
    }
    int ns = *spill_cnt; if (ns > SPILL_MAX) ns = SPILL_MAX;
    for (int i = tid; i < ns; i += 256) {
        int4 q = sp[i];
        if ((q.y >> 7) == b) atomicAdd(&wacc[q.y & 127], __int_as_float(q.z));
    }
    __syncthreads();
    // inclusive prefix over hist -> pref
    if (tid < BNODES) pref[tid] = hist[tid];
    __syncthreads();
    for (int off = 1; off < BNODES; off <<= 1) {
        int v = 0;
        if (tid < BNODES && tid >= off) v = pref[tid - off];
        __syncthreads();
        if (tid < BNODES) pref[tid] += v;
        __syncthreads();
    }
    if (tid < BNODES) curs[tid] = pref[tid] - hist[tid];   // exclusive start
    if (tid < n) {
        row_beg[lo + tid] = b * (BCAP * 2) + (pref[tid] - hist[tid]);
        row_cnt[lo + tid] = hist[tid];
        dinv[lo + tid] = rsqrtf(1.0f + wacc[tid]);
    }
    __syncthreads();
    // scatter node-sorted 4B entries over the bucket's own region (source is in LDS)
    uint* outb = (uint*)ebuf + (size_t)b * (BCAP * 2);
    for (int j = tid; j < cnt; j += 256) {
        uint2 e = ent[j];
        int nl = e.x >> 17;
        int pos = atomicAdd(&curs[nl], 1);
        uint wq = __float2uint_rn(__uint_as_float(e.y) * WQSCALE);
        outb[pos] = (wq << 17) | (e.x & 0x1FFFF);
    }
}

// fold dinv[src] into each sorted entry: q15(w) -> q15(dinv[s]*w)
__global__ __launch_bounds__(256) void k_nrm(uint* __restrict__ sbuf,
                                             const int* __restrict__ bucket_cnt,
                                             const float* __restrict__ dinv) {
    int b = blockIdx.x, tid = threadIdx.x;
    int cnt = bucket_cnt[b]; if (cnt > BCAP) cnt = BCAP;
    uint* outb = sbuf + (size_t)b * (BCAP * 2);
    for (int j = tid; j < cnt; j += 256) {
        uint e = outb[j];
        int s = e & 0x1FFFF;
        float wv = (float)(e >> 17) * (1.0f / WQSCALE);
        uint q = __float2uint_rn(dinv[s] * wv * WQSCALE);
        outb[j] = (q << 17) | (uint)s;
    }
}

// fused: layer-1 gather (fp16 x, 16 edges x 4 channel-groups) + self + MLP.
// entry q15 = dinv[s]*w; node total = di * (sum q*x[s] + di*x_self + spill)
__global__ __launch_bounds__(256) void k_gather_mlp(const uint* __restrict__ sbuf,
                                                    const int* __restrict__ row_beg,
                                                    const int* __restrict__ row_cnt,
                                                    const int4* __restrict__ sp,
                                                    const int* __restrict__ spill_cnt,
                                                    const float* __restrict__ dinv,
                                                    const __half* __restrict__ x16,
                                                    const float* __restrict__ W1,
                                                    const float* __restrict__ b1,
                                                    const float* __restrict__ W2,
                                                    const float* __restrict__ b2,
                                                    __half* __restrict__ h2,
                                                    float* __restrict__ out) {
    __shared__ float fvs[4][16];
    __shared__ float o1s[4][128];
    int wave = threadIdx.x >> 6, lane = threadIdx.x & 63;
    int node = (blockIdx.x & 7) * NPX + (blockIdx.x >> 3) * 4 + wave;  // XCD slab
    int c4 = lane & 3, eo = lane >> 2;
    int beg = row_beg[node], cnt = row_cnt[node];
    float di = dinv[node];
    const uint* row = sbuf + beg;
    float4 acc = make_float4(0.f, 0.f, 0.f, 0.f);
    int j = eo;
    uint e = (j < cnt) ? __builtin_nontemporal_load(row + j) : 0u;
    while (j < cnt) {
        uint ec = e;
        j += 16;
        if (j < cnt) e = __builtin_nontemporal_load(row + j);   // prefetch next
        int s = ec & 0x1FFFF;
        float nq = (float)(ec >> 17) * (1.0f / WQSCALE);
        uint2 hv = *(const uint2*)(x16 + (size_t)s * 16 + c4 * 4);
        float2 f01 = __half22float2(*(__half2*)&hv.x);
        float2 f23 = __half22float2(*(__half2*)&hv.y);
        acc.x = fmaf(nq, f01.x, acc.x);
        acc.y = fmaf(nq, f01.y, acc.y);
        acc.z = fmaf(nq, f23.x, acc.z);
        acc.w = fmaf(nq, f23.y, acc.w);
    }
#pragma unroll
    for (int m = 4; m < 64; m <<= 1) {
        acc.x += __shfl_xor(acc.x, m, 64);
        acc.y += __shfl_xor(acc.y, m, 64);
        acc.z += __shfl_xor(acc.z, m, 64);
        acc.w += __shfl_xor(acc.w, m, 64);
    }
    if (lane < 4) {
        uint2 hv = *(const uint2*)(x16 + (size_t)node * 16 + lane * 4);
        float2 s01 = __half22float2(*(__half2*)&hv.x);
        float2 s23 = __half22float2(*(__half2*)&hv.y);
        float4 r;
        r.x = acc.x + di * s01.x;
        r.y = acc.y + di * s01.y;
        r.z = acc.z + di * s23.x;
        r.w = acc.w + di * s23.y;
        int ns = *spill_cnt;                       // 0 in practice
        if (ns > 0) {
            if (ns > SPILL_MAX) ns = SPILL_MAX;
            for (int i = 0; i < ns; i++) {
                int4 q = sp[i];
                if (q.y == node) {
                    float f = dinv[q.x] * __int_as_float(q.z);
                    uint2 qv = *(const uint2*)(x16 + (size_t)q.x * 16 + lane * 4);
                    float2 a01 = __half22float2(*(__half2*)&qv.x);
                    float2 a23 = __half22float2(*(__half2*)&qv.y);
                    r.x += f * a01.x; r.y += f * a01.y;
                    r.z += f * a23.x; r.w += f * a23.y;
                }
            }
        }
        r.x *= di; r.y *= di; r.z *= di; r.w *= di;
        *(float4*)&fvs[wave][lane * 4] = r;
    }
    __syncthreads();
    float fv[16];
#pragma unroll
    for (int k = 0; k < 16; k++) fv[k] = fvs[wave][k];
    float a = b1[2 * lane], bb = b1[2 * lane + 1];
#pragma unroll
    for (int k = 0; k < 16; k++) {
        float2 wv = *(const float2*)(W1 + k * 128 + 2 * lane);
        a = fmaf(fv[k], wv.x, a);
        bb = fmaf(fv[k], wv.y, bb);
    }
    o1s[wave][2 * lane + 0] = fmaxf(a, 0.0f);
    o1s[wave][2 * lane + 1] = fmaxf(bb, 0.0f);
    __syncthreads();
    int c = lane & 15, g = lane >> 4;
    float p = 0.0f;
#pragma unroll
    for (int k = 0; k < 32; k++) {
        int kk = g * 32 + k;
        p = fmaf(o1s[wave][kk], W2[kk * 16 + c], p);
    }
    p += __shfl_down(p, 16, 64);
    p += __shfl_down(p, 32, 64);
    if (lane < 16) {
        h2[(size_t)node * 16 + c] = __float2half(p);
        out[(size_t)node * 16 + c] = di * di * p + b2[c];
    }
}

// layer-2 gather: out[node] += di * (sum q*h2[s] + spill)
__global__ __launch_bounds__(256) void k_gather2(const uint* __restrict__ sbuf,
                                                 const int* __restrict__ row_beg,
                                                 const int* __restrict__ row_cnt,
                                                 const int4* __restrict__ sp,
                                                 const int* __restrict__ spill_cnt,
                                                 const float* __restrict__ dinv,
                                                 const __half* __restrict__ h2,
                                                 float* __restrict__ out) {
    int wave = threadIdx.x >> 6, lane = threadIdx.x & 63;
    int node = (blockIdx.x & 7) * NPX + (blockIdx.x >> 3) * 4 + wave;
    int c4 = lane & 3, eo = lane >> 2;
    int beg = row_beg[node], cnt = row_cnt[node];
    float di = dinv[node];
    const uint* row = sbuf + beg;
    float4 acc = make_float4(0.f, 0.f, 0.f, 0.f);
    int j = eo;
    uint e = (j < cnt) ? __builtin_nontemporal_load(row + j) : 0u;
    while (j < cnt) {
        uint ec = e;
        j += 16;
        if (j < cnt) e = __builtin_nontemporal_load(row + j);
        int s = ec & 0x1FFFF;
        float nq = (float)(ec >> 17) * (1.0f / WQSCALE);
        uint2 hv = *(const uint2*)(h2 + (size_t)s * 16 + c4 * 4);
        float2 f01 = __half22float2(*(__half2*)&hv.x);
        float2 f23 = __half22float2(*(__half2*)&hv.y);
        acc.x = fmaf(nq, f01.x, acc.x);
        acc.y = fmaf(nq, f01.y, acc.y);
        acc.z = fmaf(nq, f23.x, acc.z);
        acc.w = fmaf(nq, f23.y, acc.w);
    }
#pragma unroll
    for (int m = 4; m < 64; m <<= 1) {
        acc.x += __shfl_xor(acc.x, m, 64);
        acc.y += __shfl_xor(acc.y, m, 64);
        acc.z += __shfl_xor(acc.z, m, 64);
        acc.w += __shfl_xor(acc.w, m, 64);
    }
    if (lane < 4) {
        int ns = *spill_cnt;
        if (ns > 0) {
            if (ns > SPILL_MAX) ns = SPILL_MAX;
            for (int i = 0; i < ns; i++) {
                int4 q = sp[i];
                if (q.y == node) {
                    float f = dinv[q.x] * __int_as_float(q.z);
                    uint2 qv = *(const uint2*)(h2 + (size_t)q.x * 16 + lane * 4);
                    float2 a01 = __half22float2(*(__half2*)&qv.x);
                    float2 a23 = __half22float2(*(__half2*)&qv.y);
                    acc.x += f * a01.x; acc.y += f * a01.y;
                    acc.z += f * a23.x; acc.w += f * a23.y;
                }
            }
        }
        float4 o = *(float4*)(out + (size_t)node * 16 + lane * 4);
        o.x += di * acc.x; o.y += di * acc.y;
        o.z += di * acc.z; o.w += di * acc.w;
        *(float4*)(out + (size_t)node * 16 + lane * 4) = o;
    }
}

// ===================== CSR fallback (round-2) =====================

__global__ void k_init(float* __restrict__ deg, int* __restrict__ cnt) {
    int i = blockIdx.x * blockDim.x + threadIdx.x;
    if (i < N_NODES) { deg[i] = 1.0f; if (cnt) cnt[i] = 0; }
}

__global__ void k_degcnt(const int* __restrict__ dst, const float* __restrict__ w,
                         float* __restrict__ deg, int* __restrict__ cnt) {
    int e = blockIdx.x * blockDim.x + threadIdx.x;
    if (e < N_EDGES) {
        int d = dst[e];
        atomicAdd(&deg[d], w[e]);
        if (cnt) atomicAdd(&cnt[d], 1);
    }
}

__global__ void k_dinv_agg(const float* __restrict__ x, float* __restrict__ deg_dinv,
                           float* __restrict__ agg) {
    int i = blockIdx.x * blockDim.x + threadIdx.x;
    if (i >= N_NODES) return;
    float di = rsqrtf(deg_dinv[i]);
    deg_dinv[i] = di;
    float s = di * di;
    const float4* xr = (const float4*)(x + (size_t)i * 16);
    float4* ar = (float4*)(agg + (size_t)i * 16);
#pragma unroll
    for (int k = 0; k < 4; k++) {
        float4 v = xr[k];
        v.x *= s; v.y *= s; v.z *= s; v.w *= s;
        ar[k] = v;
    }
}

__global__ __launch_bounds__(256) void k_scan1(const int* __restrict__ cnt,
                                               int* __restrict__ rowptr,
                                               int* __restrict__ bsum) {
    __shared__ int ts[256];
    int tid = threadIdx.x;
    int base = blockIdx.x * SCAN_CHUNK + tid * 8;
    int v[8]; int s = 0;
#pragma unroll
    for (int k = 0; k < 8; k++) {
        int idx = base + k;
        v[k] = (idx < N_NODES) ? cnt[idx] : 0;
        s += v[k];
    }
    ts[tid] = s;
    __syncthreads();
    for (int off = 1; off < 256; off <<= 1) {
        int t = (tid >= off) ? ts[tid - off] : 0;
        __syncthreads();
        ts[tid] += t;
        __syncthreads();
    }
    int run = ts[tid] - s;
#pragma unroll
    for (int k = 0; k < 8; k++) {
        int idx = base + k;
        if (idx < N_NODES) rowptr[idx] = run;
        run += v[k];
    }
    if (tid == 255) bsum[blockIdx.x] = ts[255];
}

__global__ void k_scan2(int* __restrict__ bsum) {
    if (threadIdx.x == 0 && blockIdx.x == 0) {
        int run = 0;
        for (int g = 0; g < SCAN_BLOCKS; g++) { int t = bsum[g]; bsum[g] = run; run += t; }
    }
}

__global__ __launch_bounds__(256) void k_scan3(int* __restrict__ rowptr,
                                               const int* __restrict__ bsum) {
    int tid = threadIdx.x;
    int base = blockIdx.x * SCAN_CHUNK + tid * 8;
    int off = bsum[blockIdx.x];
#pragma unroll
    for (int k = 0; k < 8; k++) {
        int idx = base + k;
        if (idx < N_NODES) rowptr[idx] += off;
    }
    if (blockIdx.x == 0 && tid == 0) rowptr[N_NODES] = N_EDGES;
}

__global__ void k_fill(const int* __restrict__ src, const int* __restrict__ dst,
                       const float* __restrict__ w, const float* __restrict__ dinv,
                       const int* __restrict__ rowptr, int* __restrict__ cnt,
                       int2* __restrict__ perm) {
    int e = blockIdx.x * blockDim.x + threadIdx.x;
    if (e >= N_EDGES) return;
    int s = src[e], d = dst[e];
    float nrm = dinv[s] * w[e] * dinv[d];
    int r = atomicSub(&cnt[d], 1) - 1;
    int pos = rowptr[d] + r;
    perm[pos] = make_int2(s, __float_as_int(nrm));
}

__global__ __launch_bounds__(256) void k_gather(const int2* __restrict__ perm,
                                                const int* __restrict__ rowptr,
                                                const float* __restrict__ feat,
                                                float* __restrict__ out) {
    int wave = threadIdx.x >> 6, lane = threadIdx.x & 63;
    int node = blockIdx.x * 4 + wave;
    int c = lane & 15, eo = lane >> 4;
    int beg = rowptr[node], end = rowptr[node + 1];
    float acc = 0.0f;
    for (int j = beg + eo; j < end; j += 4) {
        int2 ed = perm[j];
        acc = fmaf(__int_as_float(ed.y), feat[(size_t)ed.x * 16 + c], acc);
    }
    acc += __shfl_xor(acc, 16, 64);
    acc += __shfl_xor(acc, 32, 64);
    if (lane < 16) out[(size_t)node * 16 + c] += acc;
}

__global__ __launch_bounds__(256) void k_mlp(float* __restrict__ agg,
                                             const float* __restrict__ W1,
                                             const float* __restrict__ b1,
                                             const float* __restrict__ W2,
                                             const float* __restrict__ b2,
                                             const float* __restrict__ dinv,
                                             float* __restrict__ out) {
    __shared__ float o1s[4][128];
    int wave = threadIdx.x >> 6;
    int lane = threadIdx.x & 63;
    int node = blockIdx.x * 4 + wave;
    const float* f = agg + (size_t)node * 16;
    float fv[16];
#pragma unroll
    for (int k = 0; k < 4; k++) {
        float4 v = ((const float4*)f)[k];
        fv[4 * k + 0] = v.x; fv[4 * k + 1] = v.y; fv[4 * k + 2] = v.z; fv[4 * k + 3] = v.w;
    }
    float a = b1[2 * lane], b = b1[2 * lane + 1];
#pragma unroll
    for (int k = 0; k < 16; k++) {
        float2 wv = *(const float2*)(W1 + k * 128 + 2 * lane);
        a = fmaf(fv[k], wv.x, a);
        b = fmaf(fv[k], wv.y, b);
    }
    o1s[wave][2 * lane + 0] = fmaxf(a, 0.0f);
    o1s[wave][2 * lane + 1] = fmaxf(b, 0.0f);
    __syncthreads();
    int c = lane & 15, g = lane >> 4;
    float p = 0.0f;
#pragma unroll
    for (int k = 0; k < 32; k++) {
        int kk = g * 32 + k;
        p = fmaf(o1s[wave][kk], W2[kk * 16 + c], p);
    }
    p += __shfl_down(p, 16, 64);
    p += __shfl_down(p, 32, 64);
    __syncthreads();
    if (lane < 16) {
        float h2v = p;
        agg[(size_t)node * 16 + c] = h2v;
        float di = dinv[node];
        out[(size_t)node * 16 + c] = di * di * h2v + b2[c];
    }
}

__global__ void k_scatter(const int* __restrict__ src, const int* __restrict__ dst,
                          const float* __restrict__ w, const float* __restrict__ dinv,
                          const float* __restrict__ feat, float* __restrict__ out) {
    int t = blockIdx.x * blockDim.x + threadIdx.x;
    int e = t >> 2;
    int c4 = (t & 3) * 4;
    if (e >= N_EDGES) return;
    int s = src[e], d = dst[e];
    float nrm = dinv[s] * w[e] * dinv[d];
    float4 v = *(const float4*)(feat + (size_t)s * 16 + c4);
    float* o = out + (size_t)d * 16 + c4;
    atomicAdd(o + 0, nrm * v.x);
    atomicAdd(o + 1, nrm * v.y);
    atomicAdd(o + 2, nrm * v.z);
    atomicAdd(o + 3, nrm * v.w);
}

// ===================== launch =====================

extern "C" void kernel_launch(void* const* d_in, const int* in_sizes, int n_in,
                              void* d_out, int out_size, void* d_ws, size_t ws_size,
                              hipStream_t stream) {
    const float* x  = (const float*)d_in[0];
    const int*   ei = (const int*)d_in[1];
    const float* w  = (const float*)d_in[2];
    const float* W1 = (const float*)d_in[3];
    const float* b1 = (const float*)d_in[4];
    const float* W2 = (const float*)d_in[5];
    const float* b2 = (const float*)d_in[6];
    float* out = (float*)d_out;

    const int* src = ei;
    const int* dst = ei + N_EDGES;
    const int B = 256;

    // ---- fast-path workspace layout (16B-aligned blocks) ----
    char* p = (char*)d_ws;
    int*    bucket_cnt = (int*)p;        p += (size_t)((NBUCK + 3) & ~3) * 4;
    int*    spill_cnt  = (int*)p;        p += 16;
    float*  dinv       = (float*)p;      p += (size_t)N_PAD * 4;
    int*    row_beg    = (int*)p;        p += (size_t)N_PAD * 4;
    int*    row_cnt    = (int*)p;        p += (size_t)N_PAD * 4;
    __half* x16        = (__half*)p;     p += (size_t)N_NODES * 16 * 2;
    __half* h2         = (__half*)p;     p += (size_t)N_NODES * 16 * 2;
    int4*   sp         = (int4*)p;       p += (size_t)SPILL_MAX * 16;
    uint2*  ebuf       = (uint2*)p;      p += (size_t)NBUCK * BCAP * 8;
    const size_t WS_FAST = (size_t)(p - (char*)d_ws);

    if (ws_size >= WS_FAST) {
        k_pre<<<(N_NODES * 16 + B - 1) / B, B, 0, stream>>>(x, x16, bucket_cnt, spill_cnt);
        k_bin<<<BIN_BLOCKS, B, 0, stream>>>(src, dst, w, bucket_cnt, ebuf, sp, spill_cnt);
        k_sort<<<NBUCK, B, 0, stream>>>(ebuf, bucket_cnt, sp, spill_cnt,
                                        dinv, row_beg, row_cnt);
        k_nrm<<<NBUCK, B, 0, stream>>>((uint*)ebuf, bucket_cnt, dinv);
        k_gather_mlp<<<N_NODES / 4, B, 0, stream>>>((const uint*)ebuf, row_beg, row_cnt,
                                                    sp, spill_cnt, dinv, x16,
                                                    W1, b1, W2, b2, h2, out);
        k_gather2<<<N_NODES / 4, B, 0, stream>>>((const uint*)ebuf, row_beg, row_cnt,
                                                 sp, spill_cnt, dinv, h2, out);
        return;
    }

    // ---- CSR fallback (round-2 path) ----
    float* deg_dinv = (float*)d_ws;
    int*   cntb     = (int*)(deg_dinv + N_PAD);
    int*   rowptr   = cntb + N_PAD;
    int*   bsum     = rowptr + N_PAD;
    float* agg      = (float*)(bsum + 64);
    int2*  perm     = (int2*)(agg + (size_t)N_NODES * 16);
    const size_t WS_CSR = ((size_t)N_PAD * 3 + 64 + (size_t)N_NODES * 16) * 4
                          + (size_t)N_EDGES * 8;

    if (ws_size >= WS_CSR) {
        k_init<<<(N_NODES + B - 1) / B, B, 0, stream>>>(deg_dinv, cntb);
        k_degcnt<<<(N_EDGES + B - 1) / B, B, 0, stream>>>(dst, w, deg_dinv, cntb);
        k_dinv_agg<<<(N_NODES + B - 1) / B, B, 0, stream>>>(x, deg_dinv, agg);
        k_scan1<<<SCAN_BLOCKS, 256, 0, stream>>>(cntb, rowptr, bsum);
        k_scan2<<<1, 64, 0, stream>>>(bsum);
        k_scan3<<<SCAN_BLOCKS, 256, 0, stream>>>(rowptr, bsum);
        k_fill<<<(N_EDGES + B - 1) / B, B, 0, stream>>>(src, dst, w, deg_dinv,
                                                        rowptr, cntb, perm);
        k_gather<<<N_NODES / 4, B, 0, stream>>>(perm, rowptr, x, agg);
        k_mlp<<<N_NODES / 4, B, 0, stream>>>(agg, W1, b1, W2, b2, deg_dinv, out);
        k_gather<<<N_NODES / 4, B, 0, stream>>>(perm, rowptr, agg, out);
    } else {
        float* deg = (float*)d_ws;
        float* ag  = (float*)d_ws + N_NODES;
        k_init<<<(N_NODES + B - 1) / B, B, 0, stream>>>(deg, (int*)nullptr);
        k_degcnt<<<(N_EDGES + B - 1) / B, B, 0, stream>>>(dst, w, deg, (int*)nullptr);
        k_dinv_agg<<<(N_NODES + B - 1) / B, B, 0, stream>>>(x, deg, ag);
        k_scatter<<<((size_t)N_EDGES * 4 + B - 1) / B, B, 0, stream>>>(src, dst, w, deg, x, ag);
        k_mlp<<<N_NODES / 4, B, 0, stream>>>(ag, W1, b1, W2, b2, deg, out);
        k_scatter<<<((size_t)N_EDGES * 4 + B - 1) / B, B, 0, stream>>>(src, dst, w, deg, ag, out);
    }
}

// Round 9
// 383.995 us; speedup vs baseline: 2.2793x; 1.0161x over previous
//
#include <hip/hip_runtime.h>
#include <hip/hip_fp16.h>

#define N_NODES 100000
#define N_EDGES 3200000
#define N_PAD   100096
#define BNODES  128
#define NBUCK   ((N_NODES + BNODES - 1) / BNODES)       // 782
#define BCAP    4800                                    // mean 4096, sigma 64 (11 sigma)
#define EPB_BIN 8192                                    // edges per bin block (32/thread)
#define BIN_BLOCKS ((N_EDGES + EPB_BIN - 1) / EPB_BIN)  // 391
#define SPILL_MAX 65536
#define WQSCALE  32767.0f
#define NPX      (N_NODES / 8)                          // 12500 nodes per XCD slab
#define SCAN_CHUNK 2048
#define SCAN_BLOCKS ((N_NODES + SCAN_CHUNK - 1) / SCAN_CHUNK)

typedef unsigned int uint;

// ===================== fast path: bin -> sort -> nrm -> gather =====================

// prologue: x -> fp16, zero bucket_cnt/spill_cnt
__global__ __launch_bounds__(256) void k_pre(const float* __restrict__ x,
                                             __half* __restrict__ x16,
                                             int* __restrict__ bucket_cnt,
                                             int* __restrict__ spill_cnt) {
    int i = blockIdx.x * blockDim.x + threadIdx.x;
    if (i < N_NODES * 16) x16[i] = __float2half(x[i]);
    if (i < NBUCK) bucket_cnt[i] = 0;
    if (i == 0) *spill_cnt = 0;
}

// counting-sort edges into 782 dst-buckets; entry = { (dstl<<17)|src , w_bits }
__global__ __launch_bounds__(256) void k_bin(const int* __restrict__ src,
                                             const int* __restrict__ dst,
                                             const float* __restrict__ w,
                                             int* __restrict__ bucket_cnt,
                                             uint2* __restrict__ ebuf,
                                             int4* __restrict__ sp,
                                             int* __restrict__ spill_cnt) {
    __shared__ int hist[NBUCK];
    __shared__ int base[NBUCK];
    __shared__ int rank[NBUCK];
    int tid = threadIdx.x;
    for (int b = tid; b < NBUCK; b += 256) { hist[b] = 0; rank[b] = 0; }
    __syncthreads();
    int e0 = blockIdx.x * EPB_BIN;
#pragma unroll 4
    for (int k = 0; k < 32; k++) {
        int e = e0 + tid + k * 256;
        if (e < N_EDGES) atomicAdd(&hist[__builtin_nontemporal_load(dst + e) >> 7], 1);
    }
    __syncthreads();
    for (int b = tid; b < NBUCK; b += 256) {
        int c = hist[b];
        base[b] = c ? atomicAdd(&bucket_cnt[b], c) : 0;
    }
    __syncthreads();
#pragma unroll 4
    for (int k = 0; k < 32; k++) {
        int e = e0 + tid + k * 256;
        if (e < N_EDGES) {
            int s = __builtin_nontemporal_load(src + e);
            int d = __builtin_nontemporal_load(dst + e);
            float wv = __builtin_nontemporal_load(w + e);
            int b = d >> 7;
            int r = atomicAdd(&rank[b], 1);
            int pos = base[b] + r;
            if (pos < BCAP) {
                ebuf[(size_t)b * BCAP + pos] =
                    make_uint2(((uint)(d & 127) << 17) | (uint)s, __float_as_uint(wv));
            } else {
                int oi = atomicAdd(spill_cnt, 1);
                if (oi < SPILL_MAX) sp[oi] = make_int4(s, d, __float_as_int(wv), 0);
            }
        }
    }
}

// per-bucket: stage in LDS, node-histogram + weighted degree, prefix, scatter to
// node-major 4B entries (overlaying the bucket's own ebuf region), write dinv/rowptr.
__global__ __launch_bounds__(256) void k_sort(uint2* __restrict__ ebuf,
                                              const int* __restrict__ bucket_cnt,
                                              const int4* __restrict__ sp,
                                              const int* __restrict__ spill_cnt,
                                              float* __restrict__ dinv,
                                              int* __restrict__ row_beg,
                                              int* __restrict__ row_cnt) {
    __shared__ uint2 ent[BCAP];          // 38.4 KB
    __shared__ float wacc[BNODES];
    __shared__ int   hist[BNODES];
    __shared__ int   pref[BNODES];
    __shared__ int   curs[BNODES];
    int b = blockIdx.x, tid = threadIdx.x;
    int lo = b * BNODES;
    int n = N_NODES - lo; if (n > BNODES) n = BNODES;
    if (tid < BNODES) { wacc[tid] = 0.0f; hist[tid] = 0; }
    __syncthreads();
    int cnt = bucket_cnt[b]; if (cnt > BCAP) cnt = BCAP;
    const uint2* srcrow = ebuf + (size_t)b * BCAP;
    for (int j = tid; j < cnt; j += 256) {
        uint2 e = srcrow[j];
        ent[j] = e;
        int nl = e.x >> 17;
        atomicAdd(&hist[nl], 1);
        atomicAdd(&wacc[nl], __uint_as_float(e.y));
    }
    int ns = *spill_cnt; if (ns > SPILL_MAX) ns = SPILL_MAX;
    for (int i = tid; i < ns; i += 256) {
        int4 q = sp[i];
        if ((q.y >> 7) == b) atomicAdd(&wacc[q.y & 127], __int_as_float(q.z));
    }
    __syncthreads();
    // inclusive prefix over hist -> pref
    if (tid < BNODES) pref[tid] = hist[tid];
    __syncthreads();
    for (int off = 1; off < BNODES; off <<= 1) {
        int v = 0;
        if (tid < BNODES && tid >= off) v = pref[tid - off];
        __syncthreads();
        if (tid < BNODES) pref[tid] += v;
        __syncthreads();
    }
    if (tid < BNODES) curs[tid] = pref[tid] - hist[tid];   // exclusive start
    if (tid < n) {
        row_beg[lo + tid] = b * (BCAP * 2) + (pref[tid] - hist[tid]);
        row_cnt[lo + tid] = hist[tid];
        dinv[lo + tid] = rsqrtf(1.0f + wacc[tid]);
    }
    __syncthreads();
    // scatter node-sorted 4B entries over the bucket's own region (source is in LDS)
    uint* outb = (uint*)ebuf + (size_t)b * (BCAP * 2);
    for (int j = tid; j < cnt; j += 256) {
        uint2 e = ent[j];
        int nl = e.x >> 17;
        int pos = atomicAdd(&curs[nl], 1);
        uint wq = __float2uint_rn(__uint_as_float(e.y) * WQSCALE);
        outb[pos] = (wq << 17) | (e.x & 0x1FFFF);
    }
}

// fold dinv[src] into each sorted entry: q15(w) -> q15(dinv[s]*w)
__global__ __launch_bounds__(256) void k_nrm(uint* __restrict__ sbuf,
                                             const int* __restrict__ bucket_cnt,
                                             const float* __restrict__ dinv) {
    int b = blockIdx.x, tid = threadIdx.x;
    int cnt = bucket_cnt[b]; if (cnt > BCAP) cnt = BCAP;
    uint* outb = sbuf + (size_t)b * (BCAP * 2);
    for (int j = tid; j < cnt; j += 256) {
        uint e = outb[j];
        int s = e & 0x1FFFF;
        float wv = (float)(e >> 17) * (1.0f / WQSCALE);
        uint q = __float2uint_rn(dinv[s] * wv * WQSCALE);
        outb[j] = (q << 17) | (uint)s;
    }
}

// fused: layer-1 gather (fp16 x, 32 edges x 2 channel-groups) + self + MLP.
// entry q15 = dinv[s]*w; node total = di * (sum q*x[s] + di*x_self + spill)
__global__ __launch_bounds__(256) void k_gather_mlp(const uint* __restrict__ sbuf,
                                                    const int* __restrict__ row_beg,
                                                    const int* __restrict__ row_cnt,
                                                    const int4* __restrict__ sp,
                                                    const int* __restrict__ spill_cnt,
                                                    const float* __restrict__ dinv,
                                                    const __half* __restrict__ x16,
                                                    const float* __restrict__ W1,
                                                    const float* __restrict__ b1,
                                                    const float* __restrict__ W2,
                                                    const float* __restrict__ b2,
                                                    __half* __restrict__ h2,
                                                    float* __restrict__ out) {
    __shared__ float fvs[4][16];
    __shared__ float o1s[4][128];
    int wave = threadIdx.x >> 6, lane = threadIdx.x & 63;
    int node = (blockIdx.x & 7) * NPX + (blockIdx.x >> 3) * 4 + wave;  // XCD slab
    int c2 = lane & 1, eo = lane >> 1;
    int beg = row_beg[node], cnt = row_cnt[node];
    float di = dinv[node];
    const uint* row = sbuf + beg;
    float acc[8];
#pragma unroll
    for (int k = 0; k < 8; k++) acc[k] = 0.0f;
    int j = eo;
    uint e = (j < cnt) ? __builtin_nontemporal_load(row + j) : 0u;
    while (j < cnt) {
        uint ec = e;
        j += 32;
        if (j < cnt) e = __builtin_nontemporal_load(row + j);   // prefetch next
        int s = ec & 0x1FFFF;
        float nq = (float)(ec >> 17) * (1.0f / WQSCALE);
        uint4 hv = *(const uint4*)(x16 + (size_t)s * 16 + c2 * 8);
        float2 f0 = __half22float2(*(__half2*)&hv.x);
        float2 f1 = __half22float2(*(__half2*)&hv.y);
        float2 f2 = __half22float2(*(__half2*)&hv.z);
        float2 f3 = __half22float2(*(__half2*)&hv.w);
        acc[0] = fmaf(nq, f0.x, acc[0]);
        acc[1] = fmaf(nq, f0.y, acc[1]);
        acc[2] = fmaf(nq, f1.x, acc[2]);
        acc[3] = fmaf(nq, f1.y, acc[3]);
        acc[4] = fmaf(nq, f2.x, acc[4]);
        acc[5] = fmaf(nq, f2.y, acc[5]);
        acc[6] = fmaf(nq, f3.x, acc[6]);
        acc[7] = fmaf(nq, f3.y, acc[7]);
    }
#pragma unroll
    for (int m = 2; m < 64; m <<= 1) {
#pragma unroll
        for (int k = 0; k < 8; k++) acc[k] += __shfl_xor(acc[k], m, 64);
    }
    if (lane < 2) {
        uint4 hv = *(const uint4*)(x16 + (size_t)node * 16 + c2 * 8);
        float2 s0 = __half22float2(*(__half2*)&hv.x);
        float2 s1 = __half22float2(*(__half2*)&hv.y);
        float2 s2 = __half22float2(*(__half2*)&hv.z);
        float2 s3 = __half22float2(*(__half2*)&hv.w);
        float slf[8] = {s0.x, s0.y, s1.x, s1.y, s2.x, s2.y, s3.x, s3.y};
        float r[8];
#pragma unroll
        for (int k = 0; k < 8; k++) r[k] = acc[k] + di * slf[k];
        int ns = *spill_cnt;                       // 0 in practice
        if (ns > 0) {
            if (ns > SPILL_MAX) ns = SPILL_MAX;
            for (int i = 0; i < ns; i++) {
                int4 q = sp[i];
                if (q.y == node) {
                    float f = dinv[q.x] * __int_as_float(q.z);
                    uint4 qv = *(const uint4*)(x16 + (size_t)q.x * 16 + c2 * 8);
                    float2 a0 = __half22float2(*(__half2*)&qv.x);
                    float2 a1 = __half22float2(*(__half2*)&qv.y);
                    float2 a2 = __half22float2(*(__half2*)&qv.z);
                    float2 a3 = __half22float2(*(__half2*)&qv.w);
                    r[0] += f * a0.x; r[1] += f * a0.y;
                    r[2] += f * a1.x; r[3] += f * a1.y;
                    r[4] += f * a2.x; r[5] += f * a2.y;
                    r[6] += f * a3.x; r[7] += f * a3.y;
                }
            }
        }
#pragma unroll
        for (int k = 0; k < 8; k++) fvs[wave][c2 * 8 + k] = r[k] * di;
    }
    __syncthreads();
    float fv[16];
#pragma unroll
    for (int k = 0; k < 16; k++) fv[k] = fvs[wave][k];
    float a = b1[2 * lane], bb = b1[2 * lane + 1];
#pragma unroll
    for (int k = 0; k < 16; k++) {
        float2 wv = *(const float2*)(W1 + k * 128 + 2 * lane);
        a = fmaf(fv[k], wv.x, a);
        bb = fmaf(fv[k], wv.y, bb);
    }
    o1s[wave][2 * lane + 0] = fmaxf(a, 0.0f);
    o1s[wave][2 * lane + 1] = fmaxf(bb, 0.0f);
    __syncthreads();
    int c = lane & 15, g = lane >> 4;
    float p = 0.0f;
#pragma unroll
    for (int k = 0; k < 32; k++) {
        int kk = g * 32 + k;
        p = fmaf(o1s[wave][kk], W2[kk * 16 + c], p);
    }
    p += __shfl_down(p, 16, 64);
    p += __shfl_down(p, 32, 64);
    if (lane < 16) {
        h2[(size_t)node * 16 + c] = __float2half(p);
        out[(size_t)node * 16 + c] = di * di * p + b2[c];
    }
}

// layer-2 gather: out[node] += di * (sum q*h2[s] + spill)
__global__ __launch_bounds__(256) void k_gather2(const uint* __restrict__ sbuf,
                                                 const int* __restrict__ row_beg,
                                                 const int* __restrict__ row_cnt,
                                                 const int4* __restrict__ sp,
                                                 const int* __restrict__ spill_cnt,
                                                 const float* __restrict__ dinv,
                                                 const __half* __restrict__ h2,
                                                 float* __restrict__ out) {
    int wave = threadIdx.x >> 6, lane = threadIdx.x & 63;
    int node = (blockIdx.x & 7) * NPX + (blockIdx.x >> 3) * 4 + wave;
    int c2 = lane & 1, eo = lane >> 1;
    int beg = row_beg[node], cnt = row_cnt[node];
    float di = dinv[node];
    const uint* row = sbuf + beg;
    float acc[8];
#pragma unroll
    for (int k = 0; k < 8; k++) acc[k] = 0.0f;
    int j = eo;
    uint e = (j < cnt) ? __builtin_nontemporal_load(row + j) : 0u;
    while (j < cnt) {
        uint ec = e;
        j += 32;
        if (j < cnt) e = __builtin_nontemporal_load(row + j);
        int s = ec & 0x1FFFF;
        float nq = (float)(ec >> 17) * (1.0f / WQSCALE);
        uint4 hv = *(const uint4*)(h2 + (size_t)s * 16 + c2 * 8);
        float2 f0 = __half22float2(*(__half2*)&hv.x);
        float2 f1 = __half22float2(*(__half2*)&hv.y);
        float2 f2 = __half22float2(*(__half2*)&hv.z);
        float2 f3 = __half22float2(*(__half2*)&hv.w);
        acc[0] = fmaf(nq, f0.x, acc[0]);
        acc[1] = fmaf(nq, f0.y, acc[1]);
        acc[2] = fmaf(nq, f1.x, acc[2]);
        acc[3] = fmaf(nq, f1.y, acc[3]);
        acc[4] = fmaf(nq, f2.x, acc[4]);
        acc[5] = fmaf(nq, f2.y, acc[5]);
        acc[6] = fmaf(nq, f3.x, acc[6]);
        acc[7] = fmaf(nq, f3.y, acc[7]);
    }
#pragma unroll
    for (int m = 2; m < 64; m <<= 1) {
#pragma unroll
        for (int k = 0; k < 8; k++) acc[k] += __shfl_xor(acc[k], m, 64);
    }
    if (lane < 2) {
        int ns = *spill_cnt;
        if (ns > 0) {
            if (ns > SPILL_MAX) ns = SPILL_MAX;
            for (int i = 0; i < ns; i++) {
                int4 q = sp[i];
                if (q.y == node) {
                    float f = dinv[q.x] * __int_as_float(q.z);
                    uint4 qv = *(const uint4*)(h2 + (size_t)q.x * 16 + c2 * 8);
                    float2 a0 = __half22float2(*(__half2*)&qv.x);
                    float2 a1 = __half22float2(*(__half2*)&qv.y);
                    float2 a2 = __half22float2(*(__half2*)&qv.z);
                    float2 a3 = __half22float2(*(__half2*)&qv.w);
                    acc[0] += f * a0.x; acc[1] += f * a0.y;
                    acc[2] += f * a1.x; acc[3] += f * a1.y;
                    acc[4] += f * a2.x; acc[5] += f * a2.y;
                    acc[6] += f * a3.x; acc[7] += f * a3.y;
                }
            }
        }
        float4* op = (float4*)(out + (size_t)node * 16 + c2 * 8);
        float4 o0 = op[0], o1 = op[1];
        o0.x += di * acc[0]; o0.y += di * acc[1];
        o0.z += di * acc[2]; o0.w += di * acc[3];
        o1.x += di * acc[4]; o1.y += di * acc[5];
        o1.z += di * acc[6]; o1.w += di * acc[7];
        op[0] = o0; op[1] = o1;
    }
}

// ===================== CSR fallback (round-2) =====================

__global__ void k_init(float* __restrict__ deg, int* __restrict__ cnt) {
    int i = blockIdx.x * blockDim.x + threadIdx.x;
    if (i < N_NODES) { deg[i] = 1.0f; if (cnt) cnt[i] = 0; }
}

__global__ void k_degcnt(const int* __restrict__ dst, const float* __restrict__ w,
                         float* __restrict__ deg, int* __restrict__ cnt) {
    int e = blockIdx.x * blockDim.x + threadIdx.x;
    if (e < N_EDGES) {
        int d = dst[e];
        atomicAdd(&deg[d], w[e]);
        if (cnt) atomicAdd(&cnt[d], 1);
    }
}

__global__ void k_dinv_agg(const float* __restrict__ x, float* __restrict__ deg_dinv,
                           float* __restrict__ agg) {
    int i = blockIdx.x * blockDim.x + threadIdx.x;
    if (i >= N_NODES) return;
    float di = rsqrtf(deg_dinv[i]);
    deg_dinv[i] = di;
    float s = di * di;
    const float4* xr = (const float4*)(x + (size_t)i * 16);
    float4* ar = (float4*)(agg + (size_t)i * 16);
#pragma unroll
    for (int k = 0; k < 4; k++) {
        float4 v = xr[k];
        v.x *= s; v.y *= s; v.z *= s; v.w *= s;
        ar[k] = v;
    }
}

__global__ __launch_bounds__(256) void k_scan1(const int* __restrict__ cnt,
                                               int* __restrict__ rowptr,
                                               int* __restrict__ bsum) {
    __shared__ int ts[256];
    int tid = threadIdx.x;
    int base = blockIdx.x * SCAN_CHUNK + tid * 8;
    int v[8]; int s = 0;
#pragma unroll
    for (int k = 0; k < 8; k++) {
        int idx = base + k;
        v[k] = (idx < N_NODES) ? cnt[idx] : 0;
        s += v[k];
    }
    ts[tid] = s;
    __syncthreads();
    for (int off = 1; off < 256; off <<= 1) {
        int t = (tid >= off) ? ts[tid - off] : 0;
        __syncthreads();
        ts[tid] += t;
        __syncthreads();
    }
    int run = ts[tid] - s;
#pragma unroll
    for (int k = 0; k < 8; k++) {
        int idx = base + k;
        if (idx < N_NODES) rowptr[idx] = run;
        run += v[k];
    }
    if (tid == 255) bsum[blockIdx.x] = ts[255];
}

__global__ void k_scan2(int* __restrict__ bsum) {
    if (threadIdx.x == 0 && blockIdx.x == 0) {
        int run = 0;
        for (int g = 0; g < SCAN_BLOCKS; g++) { int t = bsum[g]; bsum[g] = run; run += t; }
    }
}

__global__ __launch_bounds__(256) void k_scan3(int* __restrict__ rowptr,
                                               const int* __restrict__ bsum) {
    int tid = threadIdx.x;
    int base = blockIdx.x * SCAN_CHUNK + tid * 8;
    int off = bsum[blockIdx.x];
#pragma unroll
    for (int k = 0; k < 8; k++) {
        int idx = base + k;
        if (idx < N_NODES) rowptr[idx] += off;
    }
    if (blockIdx.x == 0 && tid == 0) rowptr[N_NODES] = N_EDGES;
}

__global__ void k_fill(const int* __restrict__ src, const int* __restrict__ dst,
                       const float* __restrict__ w, const float* __restrict__ dinv,
                       const int* __restrict__ rowptr, int* __restrict__ cnt,
                       int2* __restrict__ perm) {
    int e = blockIdx.x * blockDim.x + threadIdx.x;
    if (e >= N_EDGES) return;
    int s = src[e], d = dst[e];
    float nrm = dinv[s] * w[e] * dinv[d];
    int r = atomicSub(&cnt[d], 1) - 1;
    int pos = rowptr[d] + r;
    perm[pos] = make_int2(s, __float_as_int(nrm));
}

__global__ __launch_bounds__(256) void k_gather(const int2* __restrict__ perm,
                                                const int* __restrict__ rowptr,
                                                const float* __restrict__ feat,
                                                float* __restrict__ out) {
    int wave = threadIdx.x >> 6, lane = threadIdx.x & 63;
    int node = blockIdx.x * 4 + wave;
    int c = lane & 15, eo = lane >> 4;
    int beg = rowptr[node], end = rowptr[node + 1];
    float acc = 0.0f;
    for (int j = beg + eo; j < end; j += 4) {
        int2 ed = perm[j];
        acc = fmaf(__int_as_float(ed.y), feat[(size_t)ed.x * 16 + c], acc);
    }
    acc += __shfl_xor(acc, 16, 64);
    acc += __shfl_xor(acc, 32, 64);
    if (lane < 16) out[(size_t)node * 16 + c] += acc;
}

__global__ __launch_bounds__(256) void k_mlp(float* __restrict__ agg,
                                             const float* __restrict__ W1,
                                             const float* __restrict__ b1,
                                             const float* __restrict__ W2,
                                             const float* __restrict__ b2,
                                             const float* __restrict__ dinv,
                                             float* __restrict__ out) {
    __shared__ float o1s[4][128];
    int wave = threadIdx.x >> 6;
    int lane = threadIdx.x & 63;
    int node = blockIdx.x * 4 + wave;
    const float* f = agg + (size_t)node * 16;
    float fv[16];
#pragma unroll
    for (int k = 0; k < 4; k++) {
        float4 v = ((const float4*)f)[k];
        fv[4 * k + 0] = v.x; fv[4 * k + 1] = v.y; fv[4 * k + 2] = v.z; fv[4 * k + 3] = v.w;
    }
    float a = b1[2 * lane], b = b1[2 * lane + 1];
#pragma unroll
    for (int k = 0; k < 16; k++) {
        float2 wv = *(const float2*)(W1 + k * 128 + 2 * lane);
        a = fmaf(fv[k], wv.x, a);
        b = fmaf(fv[k], wv.y, b);
    }
    o1s[wave][2 * lane + 0] = fmaxf(a, 0.0f);
    o1s[wave][2 * lane + 1] = fmaxf(b, 0.0f);
    __syncthreads();
    int c = lane & 15, g = lane >> 4;
    float p = 0.0f;
#pragma unroll
    for (int k = 0; k < 32; k++) {
        int kk = g * 32 + k;
        p = fmaf(o1s[wave][kk], W2[kk * 16 + c], p);
    }
    p += __shfl_down(p, 16, 64);
    p += __shfl_down(p, 32, 64);
    __syncthreads();
    if (lane < 16) {
        float h2v = p;
        agg[(size_t)node * 16 + c] = h2v;
        float di = dinv[node];
        out[(size_t)node * 16 + c] = di * di * h2v + b2[c];
    }
}

__global__ void k_scatter(const int* __restrict__ src, const int* __restrict__ dst,
                          const float* __restrict__ w, const float* __restrict__ dinv,
                          const float* __restrict__ feat, float* __restrict__ out) {
    int t = blockIdx.x * blockDim.x + threadIdx.x;
    int e = t >> 2;
    int c4 = (t & 3) * 4;
    if (e >= N_EDGES) return;
    int s = src[e], d = dst[e];
    float nrm = dinv[s] * w[e] * dinv[d];
    float4 v = *(const float4*)(feat + (size_t)s * 16 + c4);
    float* o = out + (size_t)d * 16 + c4;
    atomicAdd(o + 0, nrm * v.x);
    atomicAdd(o + 1, nrm * v.y);
    atomicAdd(o + 2, nrm * v.z);
    atomicAdd(o + 3, nrm * v.w);
}

// ===================== launch =====================

extern "C" void kernel_launch(void* const* d_in, const int* in_sizes, int n_in,
                              void* d_out, int out_size, void* d_ws, size_t ws_size,
                              hipStream_t stream) {
    const float* x  = (const float*)d_in[0];
    const int*   ei = (const int*)d_in[1];
    const float* w  = (const float*)d_in[2];
    const float* W1 = (const float*)d_in[3];
    const float* b1 = (const float*)d_in[4];
    const float* W2 = (const float*)d_in[5];
    const float* b2 = (const float*)d_in[6];
    float* out = (float*)d_out;

    const int* src = ei;
    const int* dst = ei + N_EDGES;
    const int B = 256;

    // ---- fast-path workspace layout (16B-aligned blocks) ----
    char* p = (char*)d_ws;
    int*    bucket_cnt = (int*)p;        p += (size_t)((NBUCK + 3) & ~3) * 4;
    int*    spill_cnt  = (int*)p;        p += 16;
    float*  dinv       = (float*)p;      p += (size_t)N_PAD * 4;
    int*    row_beg    = (int*)p;        p += (size_t)N_PAD * 4;
    int*    row_cnt    = (int*)p;        p += (size_t)N_PAD * 4;
    __half* x16        = (__half*)p;     p += (size_t)N_NODES * 16 * 2;
    __half* h2         = (__half*)p;     p += (size_t)N_NODES * 16 * 2;
    int4*   sp         = (int4*)p;       p += (size_t)SPILL_MAX * 16;
    uint2*  ebuf       = (uint2*)p;      p += (size_t)NBUCK * BCAP * 8;
    const size_t WS_FAST = (size_t)(p - (char*)d_ws);

    if (ws_size >= WS_FAST) {
        k_pre<<<(N_NODES * 16 + B - 1) / B, B, 0, stream>>>(x, x16, bucket_cnt, spill_cnt);
        k_bin<<<BIN_BLOCKS, B, 0, stream>>>(src, dst, w, bucket_cnt, ebuf, sp, spill_cnt);
        k_sort<<<NBUCK, B, 0, stream>>>(ebuf, bucket_cnt, sp, spill_cnt,
                                        dinv, row_beg, row_cnt);
        k_nrm<<<NBUCK, B, 0, stream>>>((uint*)ebuf, bucket_cnt, dinv);
        k_gather_mlp<<<N_NODES / 4, B, 0, stream>>>((const uint*)ebuf, row_beg, row_cnt,
                                                    sp, spill_cnt, dinv, x16,
                                                    W1, b1, W2, b2, h2, out);
        k_gather2<<<N_NODES / 4, B, 0, stream>>>((const uint*)ebuf, row_beg, row_cnt,
                                                 sp, spill_cnt, dinv, h2, out);
        return;
    }

    // ---- CSR fallback (round-2 path) ----
    float* deg_dinv = (float*)d_ws;
    int*   cntb     = (int*)(deg_dinv + N_PAD);
    int*   rowptr   = cntb + N_PAD;
    int*   bsum     = rowptr + N_PAD;
    float* agg      = (float*)(bsum + 64);
    int2*  perm     = (int2*)(agg + (size_t)N_NODES * 16);
    const size_t WS_CSR = ((size_t)N_PAD * 3 + 64 + (size_t)N_NODES * 16) * 4
                          + (size_t)N_EDGES * 8;

    if (ws_size >= WS_CSR) {
        k_init<<<(N_NODES + B - 1) / B, B, 0, stream>>>(deg_dinv, cntb);
        k_degcnt<<<(N_EDGES + B - 1) / B, B, 0, stream>>>(dst, w, deg_dinv, cntb);
        k_dinv_agg<<<(N_NODES + B - 1) / B, B, 0, stream>>>(x, deg_dinv, agg);
        k_scan1<<<SCAN_BLOCKS, 256, 0, stream>>>(cntb, rowptr, bsum);
        k_scan2<<<1, 64, 0, stream>>>(bsum);
        k_scan3<<<SCAN_BLOCKS, 256, 0, stream>>>(rowptr, bsum);
        k_fill<<<(N_EDGES + B - 1) / B, B, 0, stream>>>(src, dst, w, deg_dinv,
                                                        rowptr, cntb, perm);
        k_gather<<<N_NODES / 4, B, 0, stream>>>(perm, rowptr, x, agg);
        k_mlp<<<N_NODES / 4, B, 0, stream>>>(agg, W1, b1, W2, b2, deg_dinv, out);
        k_gather<<<N_NODES / 4, B, 0, stream>>>(perm, rowptr, agg, out);
    } else {
        float* deg = (float*)d_ws;
        float* ag  = (float*)d_ws + N_NODES;
        k_init<<<(N_NODES + B - 1) / B, B, 0, stream>>>(deg, (int*)nullptr);
        k_degcnt<<<(N_EDGES + B - 1) / B, B, 0, stream>>>(dst, w, deg, (int*)nullptr);
        k_dinv_agg<<<(N_NODES + B - 1) / B, B, 0, stream>>>(x, deg, ag);
        k_scatter<<<((size_t)N_EDGES * 4 + B - 1) / B, B, 0, stream>>>(src, dst, w, deg, x, ag);
        k_mlp<<<N_NODES / 4, B, 0, stream>>>(ag, W1, b1, W2, b2, deg, out);
        k_scatter<<<((size_t)N_EDGES * 4 + B - 1) / B, B, 0, stream>>>(src, dst, w, deg, ag, out);
    }
}